// Round 1
// baseline (3502.661 us; speedup 1.0000x reference)
//
#include <hip/hip_runtime.h>
#include <hip/hip_bf16.h>

// LlamaAttentionWithLora on MI355X — round 1: correctness-first full pipeline.
// GEMMs use bf16 MFMA 16x16x32 with 128x128 tiles (f32 global -> bf16 LDS on the fly).
// Attention in f32. Workspace layout (floats):
//   qbuf[T*H] kbuf[T*H] vbuf[T*H] attnbuf[T*H] tmpbuf[3*T*16] cos[1024*64] sin[1024*64]
// total ~171 MB.

#define H_    4096
#define NH_   32
#define HD_   128
#define T_    2592
#define DOFF_ 2560
#define DEC_  32
#define LMAX_ 512
#define RANK_ 16

__constant__ float SCALE_ = 0.08838834764831845f; // 128^-0.5

typedef __bf16 bf16x8 __attribute__((ext_vector_type(8)));
typedef __bf16 bf16x4 __attribute__((ext_vector_type(4)));
typedef float  f32x4  __attribute__((ext_vector_type(4)));

// ---------------------------------------------------------------- GEMM (C = A @ B)
// A: MxK f32 row-major (K=H_), B: KxN f32 row-major (N=H_), C: MxN f32.
// 128x128 tile, BK=32, 256 threads (4 waves, 2x2), each wave 64x64 via 4x4 16x16 frags.
__global__ __launch_bounds__(256)
void gemm_bf16(const float* __restrict__ A,
               const float* __restrict__ B0, const float* __restrict__ B1, const float* __restrict__ B2,
               float* __restrict__ C0, float* __restrict__ C1, float* __restrict__ C2, int M)
{
    const float* B; float* C;
    if      (blockIdx.z == 0) { B = B0; C = C0; }
    else if (blockIdx.z == 1) { B = B1; C = C1; }
    else                      { B = B2; C = C2; }

    const int bm0 = blockIdx.x * 128;
    const int bn0 = blockIdx.y * 128;

    __shared__ __bf16 As[128][40];   // row-major [m][k], pad 32->40 to spread banks
    __shared__ __bf16 Bs[128][40];   // transposed: Bs[n][k]

    const int tid  = threadIdx.x;
    const int lane = tid & 63;
    const int wid  = tid >> 6;
    const int wm   = (wid >> 1) * 64;
    const int wn   = (wid & 1) * 64;
    const int fr   = lane & 15;
    const int fq   = lane >> 4;

    f32x4 acc[4][4] = {};

    const int ar = tid >> 3;         // 0..31 (A stage row, +32*i)
    const int ac = (tid & 7) * 4;    // 0..28 (A stage k)
    const int bk = tid >> 5;         // 0..7  (B stage k, +8*j)
    const int bn = (tid & 31) * 4;   // 0..124(B stage n)

    for (int kt = 0; kt < H_; kt += 32) {
        // stage A (f32 -> bf16)
        #pragma unroll
        for (int i = 0; i < 4; ++i) {
            const int r  = ar + 32 * i;
            const int gr = bm0 + r;
            float4 v = (gr < M) ? *(const float4*)&A[(size_t)gr * H_ + kt + ac]
                                : make_float4(0.f, 0.f, 0.f, 0.f);
            bf16x4 w; w.x = (__bf16)v.x; w.y = (__bf16)v.y; w.z = (__bf16)v.z; w.w = (__bf16)v.w;
            *(bf16x4*)&As[r][ac] = w;
        }
        // stage B transposed
        #pragma unroll
        for (int j = 0; j < 4; ++j) {
            const int k = bk + 8 * j;
            float4 v = *(const float4*)&B[(size_t)(kt + k) * H_ + bn0 + bn];
            Bs[bn + 0][k] = (__bf16)v.x;
            Bs[bn + 1][k] = (__bf16)v.y;
            Bs[bn + 2][k] = (__bf16)v.z;
            Bs[bn + 3][k] = (__bf16)v.w;
        }
        __syncthreads();

        bf16x8 af[4], bf[4];
        #pragma unroll
        for (int i = 0; i < 4; ++i) af[i] = *(bf16x8*)&As[wm + i * 16 + fr][fq * 8];
        #pragma unroll
        for (int j = 0; j < 4; ++j) bf[j] = *(bf16x8*)&Bs[wn + j * 16 + fr][fq * 8];
        #pragma unroll
        for (int i = 0; i < 4; ++i)
            #pragma unroll
            for (int j = 0; j < 4; ++j)
                acc[i][j] = __builtin_amdgcn_mfma_f32_16x16x32_bf16(af[i], bf[j], acc[i][j], 0, 0, 0);
        __syncthreads();
    }

    // epilogue: C row = (lane>>4)*4 + reg, col = lane&15 (m89-verified layout)
    #pragma unroll
    for (int i = 0; i < 4; ++i)
        #pragma unroll
        for (int j = 0; j < 4; ++j)
            #pragma unroll
            for (int r = 0; r < 4; ++r) {
                const int row = bm0 + wm + i * 16 + fq * 4 + r;
                const int col = bn0 + wn + j * 16 + fr;
                if (row < M) C[(size_t)row * H_ + col] = acc[i][j][r];
            }
}

// ---------------------------------------------------------------- LoRA stage 1: tmp = X @ wa[seg]
__global__ __launch_bounds__(256)
void lora_tmp_kernel(const float* __restrict__ X,
                     const float* __restrict__ la0, const float* __restrict__ la1,
                     const float* __restrict__ la2, float* __restrict__ tmp)
{
    const int r = blockIdx.x;
    const int z = blockIdx.y;
    const float* la = (z == 0) ? la0 : (z == 1 ? la1 : la2);
    const int si = (r < 648) ? 0 : (r < 1296 ? 1 : (r < 1944 ? 2 : 3));
    const float* wa = la + (size_t)si * H_ * RANK_;
    const int c    = threadIdx.x & 15;
    const int part = threadIdx.x >> 4;  // 0..15, each part covers 256 h's
    const float* xr = X + (size_t)r * H_;
    float s = 0.f;
    const int h0 = part * 256;
    for (int h = h0; h < h0 + 256; ++h) s += xr[h] * wa[(size_t)h * RANK_ + c];
    __shared__ float red[16][17];
    red[part][c] = s;
    __syncthreads();
    if (threadIdx.x < 16) {
        float t = 0.f;
        #pragma unroll
        for (int p = 0; p < 16; ++p) t += red[p][threadIdx.x];
        tmp[((size_t)z * T_ + r) * RANK_ + threadIdx.x] = t;
    }
}

// ---------------------------------------------------------------- LoRA stage 2: Y += tmp @ wb[seg]
__global__ __launch_bounds__(256)
void lora_add_kernel(const float* __restrict__ tmp,
                     const float* __restrict__ lb0, const float* __restrict__ lb1,
                     const float* __restrict__ lb2,
                     float* __restrict__ Y0, float* __restrict__ Y1, float* __restrict__ Y2)
{
    const int z = blockIdx.z;
    const float* lb = (z == 0) ? lb0 : (z == 1 ? lb1 : lb2);
    float* Y = (z == 0) ? Y0 : (z == 1 ? Y1 : Y2);
    const int r = blockIdx.x;
    const int n = blockIdx.y * 256 + threadIdx.x;
    const int si = (r < 648) ? 0 : (r < 1296 ? 1 : (r < 1944 ? 2 : 3));
    const float* wb = lb + (size_t)si * RANK_ * H_;
    __shared__ float tl[16];
    if (threadIdx.x < 16) tl[threadIdx.x] = tmp[((size_t)z * T_ + r) * RANK_ + threadIdx.x];
    __syncthreads();
    float s = 0.f;
    #pragma unroll
    for (int c = 0; c < 16; ++c) s += tl[c] * wb[(size_t)c * H_ + n];
    Y[(size_t)r * H_ + n] += s;
}

// ---------------------------------------------------------------- RoPE tables (pos 0..1023)
__global__ void rope_table_kernel(float* __restrict__ cost, float* __restrict__ sint)
{
    const int p = blockIdx.x;
    const int i = threadIdx.x;  // 0..63
    const float inv = powf(10000.f, -(float)(2 * i) / (float)HD_);
    const float a = (float)p * inv;
    cost[p * 64 + i] = cosf(a);
    sint[p * 64 + i] = sinf(a);
}

// ---------------------------------------------------------------- RoPE apply (in-place)
// rows [0,DOFF): q and k at segment-relative position. rows [DOFF,T): q only, pos = kv_lens[b].
__global__ __launch_bounds__(256)
void rope_apply_kernel(float* __restrict__ q, float* __restrict__ k,
                       const int* __restrict__ kv_lens,
                       const float* __restrict__ cost, const float* __restrict__ sint)
{
    const int r = blockIdx.x;
    const int idx = blockIdx.y * 256 + threadIdx.x;   // 0..2047
    const int h = idx >> 6, i = idx & 63;
    int pos; bool dok;
    if (r < DOFF_) {
        if      (r < 1024) pos = r;
        else if (r < 1536) pos = r - 1024;
        else if (r < 2304) pos = r - 1536;
        else               pos = r - 2304;
        dok = true;
    } else {
        pos = kv_lens[r - DOFF_];
        dok = false;
    }
    const float c = cost[pos * 64 + i];
    const float s = sint[pos * 64 + i];
    const size_t base = (size_t)r * H_ + h * HD_ + i;
    float x1 = q[base], x2 = q[base + 64];
    q[base]      = x1 * c - x2 * s;
    q[base + 64] = x2 * c + x1 * s;
    if (dok) {
        x1 = k[base]; x2 = k[base + 64];
        k[base]      = x1 * c - x2 * s;
        k[base + 64] = x2 * c + x1 * s;
    }
}

// ---------------------------------------------------------------- prefill attention (f32, online softmax)
// block: 256 threads = 32 q-rows x 8 lanes; blockIdx.x in [0,80) maps to (segment, q-block).
__global__ __launch_bounds__(256)
void prefill_attn_kernel(const float* __restrict__ q, const float* __restrict__ k,
                         const float* __restrict__ v, float* __restrict__ attn)
{
    const int qb = blockIdx.x;
    int soff, slen, qoff;
    if      (qb < 32) { soff = 0;    slen = 1024; qoff = qb * 32; }
    else if (qb < 48) { soff = 1024; slen = 512;  qoff = (qb - 32) * 32; }
    else if (qb < 72) { soff = 1536; slen = 768;  qoff = (qb - 48) * 32; }
    else              { soff = 2304; slen = 256;  qoff = (qb - 72) * 32; }
    const int h = blockIdx.y;
    const int tid = threadIdx.x;
    const int rowi = tid >> 3;        // 0..31
    const int l8   = tid & 7;         // 0..7
    const int p    = qoff + rowi;     // position in segment
    const int grow = soff + p;        // global row

    __shared__ float Ks[32][HD_];
    __shared__ float Vs[32][HD_];

    float qv[16];
    const float* qr = q + (size_t)grow * H_ + h * HD_;
    #pragma unroll
    for (int u = 0; u < 4; ++u) *(float4*)&qv[u * 4] = *(const float4*)&qr[l8 * 16 + u * 4];

    float m = -1e30f, lsum = 0.f;
    float out[16];
    #pragma unroll
    for (int j = 0; j < 16; ++j) out[j] = 0.f;

    const int maxp = qoff + 31;
    for (int kt = 0; kt <= maxp; kt += 32) {
        // stage 32 K/V rows
        const int sr = tid >> 3;
        const int sc = (tid & 7) * 16;
        if (kt + sr < slen) {
            const float* kr_ = k + (size_t)(soff + kt + sr) * H_ + h * HD_ + sc;
            const float* vr_ = v + (size_t)(soff + kt + sr) * H_ + h * HD_ + sc;
            #pragma unroll
            for (int u = 0; u < 4; ++u) {
                *(float4*)&Ks[sr][sc + u * 4] = *(const float4*)&kr_[u * 4];
                *(float4*)&Vs[sr][sc + u * 4] = *(const float4*)&vr_[u * 4];
            }
        }
        __syncthreads();
        for (int kk = 0; kk < 32; ++kk) {
            const int kidx = kt + kk;
            if (kidx > p) break;   // causal; rows in an 8-lane group share p
            float d = 0.f;
            #pragma unroll
            for (int u = 0; u < 4; ++u) {
                float4 k4 = *(const float4*)&Ks[kk][l8 * 16 + u * 4];
                d += qv[u*4+0]*k4.x + qv[u*4+1]*k4.y + qv[u*4+2]*k4.z + qv[u*4+3]*k4.w;
            }
            d += __shfl_xor(d, 1); d += __shfl_xor(d, 2); d += __shfl_xor(d, 4);
            const float scv = d * SCALE_;
            const float mn  = fmaxf(m, scv);
            const float f   = __expf(m - mn);
            const float wgt = __expf(scv - mn);
            lsum = lsum * f + wgt;
            m = mn;
            #pragma unroll
            for (int u = 0; u < 4; ++u) {
                float4 v4 = *(const float4*)&Vs[kk][l8 * 16 + u * 4];
                out[u*4+0] = out[u*4+0] * f + wgt * v4.x;
                out[u*4+1] = out[u*4+1] * f + wgt * v4.y;
                out[u*4+2] = out[u*4+2] * f + wgt * v4.z;
                out[u*4+3] = out[u*4+3] * f + wgt * v4.w;
            }
        }
        __syncthreads();
    }
    const float inv = 1.f / lsum;
    float* ar = attn + (size_t)grow * H_ + h * HD_;
    #pragma unroll
    for (int j = 0; j < 16; ++j) ar[l8 * 16 + j] = out[j] * inv;
}

// ---------------------------------------------------------------- decode attention
// block per (b,h). Cache rows rope'd on the fly at slot index; row kv_lens[b] comes from new k/v.
__global__ __launch_bounds__(256)
void decode_attn_kernel(const float* __restrict__ qb_, const float* __restrict__ kb_,
                        const float* __restrict__ vb_, const float* __restrict__ kc,
                        const float* __restrict__ vc, const int* __restrict__ kv_lens,
                        const float* __restrict__ cost, const float* __restrict__ sint,
                        float* __restrict__ attn)
{
    const int b = blockIdx.x, h = blockIdx.y;
    const int kvlen = kv_lens[b];
    const int L = kvlen + 1;           // valid slots 0..kvlen inclusive
    const int tid = threadIdx.x, lane = tid & 63, w = tid >> 6;

    __shared__ float sc_s[LMAX_];
    __shared__ float red[4];
    __shared__ float oacc[HD_];

    const float* qrow = qb_ + (size_t)(DOFF_ + b) * H_ + h * HD_;
    const float q1 = qrow[lane], q2 = qrow[lane + 64];
    const float* kdrow = kb_ + (size_t)(DOFF_ + b) * H_ + h * HD_;

    for (int l = w; l < L; l += 4) {
        const float* src = (l == kvlen) ? kdrow
                                        : kc + (((size_t)b * LMAX_ + l) * NH_ + h) * HD_;
        const float k1 = src[lane], k2 = src[lane + 64];
        const float c = cost[l * 64 + lane], s = sint[l * 64 + lane];
        float d = q1 * (k1 * c - k2 * s) + q2 * (k2 * c + k1 * s);
        #pragma unroll
        for (int off = 1; off < 64; off <<= 1) d += __shfl_xor(d, off);
        if (lane == 0) sc_s[l] = d * SCALE_;
    }
    __syncthreads();

    float mx = -1e30f;
    for (int i = tid; i < L; i += 256) mx = fmaxf(mx, sc_s[i]);
    #pragma unroll
    for (int off = 1; off < 64; off <<= 1) mx = fmaxf(mx, __shfl_xor(mx, off));
    if (lane == 0) red[w] = mx;
    __syncthreads();
    mx = fmaxf(fmaxf(red[0], red[1]), fmaxf(red[2], red[3]));
    __syncthreads();

    float sum = 0.f;
    for (int i = tid; i < L; i += 256) { const float e = __expf(sc_s[i] - mx); sc_s[i] = e; sum += e; }
    #pragma unroll
    for (int off = 1; off < 64; off <<= 1) sum += __shfl_xor(sum, off);
    if (lane == 0) red[w] = sum;
    __syncthreads();
    sum = red[0] + red[1] + red[2] + red[3];
    const float inv = 1.f / sum;

    const int d = tid & 127, team = tid >> 7;
    const float* vdrow = vb_ + (size_t)(DOFF_ + b) * H_ + h * HD_;
    float acc = 0.f;
    for (int l = team; l < L; l += 2) {
        const float* src = (l == kvlen) ? vdrow
                                        : vc + (((size_t)b * LMAX_ + l) * NH_ + h) * HD_;
        acc += sc_s[l] * src[d];
    }
    if (team == 1) oacc[d] = acc;
    __syncthreads();
    if (team == 0) attn[(size_t)(DOFF_ + b) * H_ + h * HD_ + d] = (acc + oacc[d]) * inv;
}

// ---------------------------------------------------------------- host launch
extern "C" void kernel_launch(void* const* d_in, const int* in_sizes, int n_in,
                              void* d_out, int out_size, void* d_ws, size_t ws_size,
                              hipStream_t stream)
{
    const float* hs     = (const float*)d_in[0];
    const float* wq     = (const float*)d_in[1];
    const float* wk     = (const float*)d_in[2];
    const float* wv     = (const float*)d_in[3];
    const float* wo     = (const float*)d_in[4];
    const float* la_q   = (const float*)d_in[5];
    const float* lb_q   = (const float*)d_in[6];
    const float* la_k   = (const float*)d_in[7];
    const float* lb_k   = (const float*)d_in[8];
    const float* la_v   = (const float*)d_in[9];
    const float* lb_v   = (const float*)d_in[10];
    const float* la_o   = (const float*)d_in[11];
    const float* lb_o   = (const float*)d_in[12];
    const float* kcache = (const float*)d_in[13];
    const float* vcache = (const float*)d_in[14];
    const int*   kvlen  = (const int*)d_in[15];
    float* out = (float*)d_out;

    float* qbuf    = (float*)d_ws;
    float* kbuf    = qbuf + (size_t)T_ * H_;
    float* vbuf    = kbuf + (size_t)T_ * H_;
    float* attnbuf = vbuf + (size_t)T_ * H_;
    float* tmpbuf  = attnbuf + (size_t)T_ * H_;
    float* costab  = tmpbuf + (size_t)3 * T_ * RANK_;
    float* sintab  = costab + 1024 * 64;

    const int MT = (T_ + 127) / 128;  // 21

    rope_table_kernel<<<dim3(1024), dim3(64), 0, stream>>>(costab, sintab);
    gemm_bf16<<<dim3(MT, 32, 3), dim3(256), 0, stream>>>(hs, wq, wk, wv, qbuf, kbuf, vbuf, T_);
    lora_tmp_kernel<<<dim3(T_, 3), dim3(256), 0, stream>>>(hs, la_q, la_k, la_v, tmpbuf);
    lora_add_kernel<<<dim3(T_, 16, 3), dim3(256), 0, stream>>>(tmpbuf, lb_q, lb_k, lb_v, qbuf, kbuf, vbuf);
    rope_apply_kernel<<<dim3(T_, 8), dim3(256), 0, stream>>>(qbuf, kbuf, kvlen, costab, sintab);
    prefill_attn_kernel<<<dim3(80, 32), dim3(256), 0, stream>>>(qbuf, kbuf, vbuf, attnbuf);
    decode_attn_kernel<<<dim3(DEC_, NH_), dim3(256), 0, stream>>>(qbuf, kbuf, vbuf, kcache, vcache,
                                                                  kvlen, costab, sintab, attnbuf);
    gemm_bf16<<<dim3(MT, 32, 1), dim3(256), 0, stream>>>(attnbuf, wo, wo, wo, out, out, out, T_);
    lora_tmp_kernel<<<dim3(T_, 1), dim3(256), 0, stream>>>(attnbuf, la_o, la_o, la_o, tmpbuf);
    lora_add_kernel<<<dim3(T_, 16, 1), dim3(256), 0, stream>>>(tmpbuf, lb_o, lb_o, lb_o, out, out, out);
}

// Round 2
// 2342.294 us; speedup vs baseline: 1.4954x; 1.4954x over previous
//
#include <hip/hip_runtime.h>
#include <hip/hip_bf16.h>

// LlamaAttentionWithLora on MI355X — round 2.
// GEMM: m97-structure bf16 MFMA (128x128 tile, BK=32, global_load_lds w=16, linear LDS).
// Inputs pre-converted: A row-major bf16, weights transposed bf16 (k-contiguous both sides).
// Prefill attention: tile-level online softmax (1 exp/key, 1 rescale/tile).

#define H_    4096
#define NH_   32
#define HD_   128
#define T_    2592
#define DOFF_ 2560
#define DEC_  32
#define LMAX_ 512
#define RANK_ 16

__constant__ float SCALE_ = 0.08838834764831845f; // 128^-0.5

typedef __bf16 bf16x8 __attribute__((ext_vector_type(8)));
typedef __bf16 bf16x4 __attribute__((ext_vector_type(4)));
typedef float  f32x4  __attribute__((ext_vector_type(4)));

__device__ __forceinline__ void async_cp16(const __bf16* g, __bf16* l) {
    __builtin_amdgcn_global_load_lds(
        (const __attribute__((address_space(1))) void*)g,
        (__attribute__((address_space(3))) void*)l, 16, 0, 0);
}

// ---------------------------------------------------------------- f32 -> bf16 convert (row-major)
__global__ __launch_bounds__(256)
void convert_bf16_kernel(const float* __restrict__ src, __bf16* __restrict__ dst, int n8)
{
    const int stride = gridDim.x * blockDim.x;
    for (int i = blockIdx.x * blockDim.x + threadIdx.x; i < n8; i += stride) {
        float4 a = ((const float4*)src)[i * 2];
        float4 b = ((const float4*)src)[i * 2 + 1];
        bf16x8 w;
        w[0] = (__bf16)a.x; w[1] = (__bf16)a.y; w[2] = (__bf16)a.z; w[3] = (__bf16)a.w;
        w[4] = (__bf16)b.x; w[5] = (__bf16)b.y; w[6] = (__bf16)b.z; w[7] = (__bf16)b.w;
        ((bf16x8*)dst)[i] = w;
    }
}

// ---------------------------------------------------------------- f32 [K][N] -> bf16 [N][K] transpose
__global__ __launch_bounds__(256)
void transpose_bf16_kernel(const float* __restrict__ W0, const float* __restrict__ W1,
                           const float* __restrict__ W2,
                           __bf16* __restrict__ T0, __bf16* __restrict__ T1, __bf16* __restrict__ T2)
{
    const float* W = (blockIdx.z == 0) ? W0 : (blockIdx.z == 1 ? W1 : W2);
    __bf16* To     = (blockIdx.z == 0) ? T0 : (blockIdx.z == 1 ? T1 : T2);
    __shared__ float s[32][33];
    const int bx = blockIdx.x * 32;   // col of W  (= out row)
    const int by = blockIdx.y * 32;   // row of W  (= out col)
    const int r  = threadIdx.x >> 3;
    const int c4 = (threadIdx.x & 7) * 4;
    float4 v = *(const float4*)&W[(size_t)(by + r) * H_ + bx + c4];
    s[r][c4] = v.x; s[r][c4 + 1] = v.y; s[r][c4 + 2] = v.z; s[r][c4 + 3] = v.w;
    __syncthreads();
    bf16x4 o;
    o[0] = (__bf16)s[c4 + 0][r]; o[1] = (__bf16)s[c4 + 1][r];
    o[2] = (__bf16)s[c4 + 2][r]; o[3] = (__bf16)s[c4 + 3][r];
    *(bf16x4*)&To[(size_t)(bx + r) * H_ + by + c4] = o;
}

// ---------------------------------------------------------------- GEMM C = A @ Bt^T  (m97 structure)
// A: M x 4096 bf16 row-major (rows padded to 2688 in ws). Bt: 4096 x 4096 bf16, Bt[n][k].
__global__ __launch_bounds__(256)
void gemm_mfma(const __bf16* __restrict__ A,
               const __bf16* __restrict__ Bt0, const __bf16* __restrict__ Bt1,
               const __bf16* __restrict__ Bt2,
               float* __restrict__ C0, float* __restrict__ C1, float* __restrict__ C2, int M)
{
    const __bf16* Bt; float* C;
    if      (blockIdx.z == 0) { Bt = Bt0; C = C0; }
    else if (blockIdx.z == 1) { Bt = Bt1; C = C1; }
    else                      { Bt = Bt2; C = C2; }

    const int bm0 = blockIdx.x * 128;
    const int bn0 = blockIdx.y * 128;

    __shared__ __bf16 As[128 * 32];   // linear [row][k], k-contiguous (required by global_load_lds)
    __shared__ __bf16 Bs[128 * 32];   // linear [n][k]

    const int tid = threadIdx.x, lane = tid & 63, wid = tid >> 6;
    const int wm = (wid >> 1) * 64, wn = (wid & 1) * 64;
    const int fr = lane & 15, fq = lane >> 4;

    // staging map: call c covers rows c*64 + wid*16 + lane/4, k-chunk (lane%4)*8
    const int srow = wid * 16 + (lane >> 2);
    const int sk   = (lane & 3) * 8;
    const __bf16* aG = A  + (size_t)(bm0 + srow) * H_ + sk;
    const __bf16* bG = Bt + (size_t)(bn0 + srow) * H_ + sk;
    __bf16* aL = As + wid * 16 * 32;
    __bf16* bL = Bs + wid * 16 * 32;

    f32x4 acc[4][4] = {};

    for (int kt = 0; kt < H_; kt += 32) {
        async_cp16(aG + kt,                 aL);
        async_cp16(aG + kt + (size_t)64*H_, aL + 64 * 32);
        async_cp16(bG + kt,                 bL);
        async_cp16(bG + kt + (size_t)64*H_, bL + 64 * 32);
        __syncthreads();

        bf16x8 af[4], bfr[4];
        #pragma unroll
        for (int i = 0; i < 4; ++i) af[i]  = *(const bf16x8*)&As[(wm + i * 16 + fr) * 32 + fq * 8];
        #pragma unroll
        for (int j = 0; j < 4; ++j) bfr[j] = *(const bf16x8*)&Bs[(wn + j * 16 + fr) * 32 + fq * 8];
        #pragma unroll
        for (int i = 0; i < 4; ++i)
            #pragma unroll
            for (int j = 0; j < 4; ++j)
                acc[i][j] = __builtin_amdgcn_mfma_f32_16x16x32_bf16(af[i], bfr[j], acc[i][j], 0, 0, 0);
        __syncthreads();
    }

    #pragma unroll
    for (int i = 0; i < 4; ++i)
        #pragma unroll
        for (int j = 0; j < 4; ++j)
            #pragma unroll
            for (int r = 0; r < 4; ++r) {
                const int row = bm0 + wm + i * 16 + fq * 4 + r;
                const int col = bn0 + wn + j * 16 + fr;
                if (row < M) C[(size_t)row * H_ + col] = acc[i][j][r];
            }
}

// ---------------------------------------------------------------- LoRA stage 1: tmp = X @ wa[seg]
__global__ __launch_bounds__(256)
void lora_tmp_kernel(const float* __restrict__ X,
                     const float* __restrict__ la0, const float* __restrict__ la1,
                     const float* __restrict__ la2, float* __restrict__ tmp)
{
    const int r = blockIdx.x;
    const int z = blockIdx.y;
    const float* la = (z == 0) ? la0 : (z == 1 ? la1 : la2);
    const int si = (r < 648) ? 0 : (r < 1296 ? 1 : (r < 1944 ? 2 : 3));
    const float* wa = la + (size_t)si * H_ * RANK_;
    const int c    = threadIdx.x & 15;
    const int part = threadIdx.x >> 4;
    const float* xr = X + (size_t)r * H_;
    float s = 0.f;
    const int h0 = part * 256;
    for (int h = h0; h < h0 + 256; ++h) s += xr[h] * wa[(size_t)h * RANK_ + c];
    __shared__ float red[16][17];
    red[part][c] = s;
    __syncthreads();
    if (threadIdx.x < 16) {
        float t = 0.f;
        #pragma unroll
        for (int p = 0; p < 16; ++p) t += red[p][threadIdx.x];
        tmp[((size_t)z * T_ + r) * RANK_ + threadIdx.x] = t;
    }
}

// ---------------------------------------------------------------- LoRA stage 2: Y += tmp @ wb[seg]
__global__ __launch_bounds__(256)
void lora_add_kernel(const float* __restrict__ tmp,
                     const float* __restrict__ lb0, const float* __restrict__ lb1,
                     const float* __restrict__ lb2,
                     float* __restrict__ Y0, float* __restrict__ Y1, float* __restrict__ Y2)
{
    const int z = blockIdx.z;
    const float* lb = (z == 0) ? lb0 : (z == 1 ? lb1 : lb2);
    float* Y = (z == 0) ? Y0 : (z == 1 ? Y1 : Y2);
    const int r = blockIdx.x;
    const int n = blockIdx.y * 256 + threadIdx.x;
    const int si = (r < 648) ? 0 : (r < 1296 ? 1 : (r < 1944 ? 2 : 3));
    const float* wb = lb + (size_t)si * RANK_ * H_;
    __shared__ float tl[16];
    if (threadIdx.x < 16) tl[threadIdx.x] = tmp[((size_t)z * T_ + r) * RANK_ + threadIdx.x];
    __syncthreads();
    float s = 0.f;
    #pragma unroll
    for (int c = 0; c < 16; ++c) s += tl[c] * wb[(size_t)c * H_ + n];
    Y[(size_t)r * H_ + n] += s;
}

// ---------------------------------------------------------------- RoPE tables (pos 0..1023)
__global__ void rope_table_kernel(float* __restrict__ cost, float* __restrict__ sint)
{
    const int p = blockIdx.x;
    const int i = threadIdx.x;  // 0..63
    const float inv = powf(10000.f, -(float)(2 * i) / (float)HD_);
    const float a = (float)p * inv;
    cost[p * 64 + i] = cosf(a);
    sint[p * 64 + i] = sinf(a);
}

// ---------------------------------------------------------------- RoPE apply (in-place)
__global__ __launch_bounds__(256)
void rope_apply_kernel(float* __restrict__ q, float* __restrict__ k,
                       const int* __restrict__ kv_lens,
                       const float* __restrict__ cost, const float* __restrict__ sint)
{
    const int r = blockIdx.x;
    const int idx = blockIdx.y * 256 + threadIdx.x;
    const int h = idx >> 6, i = idx & 63;
    int pos; bool dok;
    if (r < DOFF_) {
        if      (r < 1024) pos = r;
        else if (r < 1536) pos = r - 1024;
        else if (r < 2304) pos = r - 1536;
        else               pos = r - 2304;
        dok = true;
    } else {
        pos = kv_lens[r - DOFF_];
        dok = false;
    }
    const float c = cost[pos * 64 + i];
    const float s = sint[pos * 64 + i];
    const size_t base = (size_t)r * H_ + h * HD_ + i;
    float x1 = q[base], x2 = q[base + 64];
    q[base]      = x1 * c - x2 * s;
    q[base + 64] = x2 * c + x1 * s;
    if (dok) {
        x1 = k[base]; x2 = k[base + 64];
        k[base]      = x1 * c - x2 * s;
        k[base + 64] = x2 * c + x1 * s;
    }
}

// ---------------------------------------------------------------- prefill attention (f32, tile-level online softmax)
__global__ __launch_bounds__(256)
void prefill_attn_kernel(const float* __restrict__ q, const float* __restrict__ k,
                         const float* __restrict__ v, float* __restrict__ attn)
{
    const int qb = blockIdx.x;
    int soff, slen, qoff;
    if      (qb < 32) { soff = 0;    slen = 1024; qoff = qb * 32; }
    else if (qb < 48) { soff = 1024; slen = 512;  qoff = (qb - 32) * 32; }
    else if (qb < 72) { soff = 1536; slen = 768;  qoff = (qb - 48) * 32; }
    else              { soff = 2304; slen = 256;  qoff = (qb - 72) * 32; }
    const int h = blockIdx.y;
    const int tid = threadIdx.x;
    const int rowi = tid >> 3;        // 0..31 (q-row)
    const int l8   = tid & 7;         // 0..7
    const int p    = qoff + rowi;
    const int grow = soff + p;

    __shared__ float Ks[32][HD_];
    __shared__ float Vs[32][HD_];

    float qv[16];
    const float* qr = q + (size_t)grow * H_ + h * HD_;
    #pragma unroll
    for (int u = 0; u < 4; ++u) *(float4*)&qv[u * 4] = *(const float4*)&qr[l8 * 16 + u * 4];

    float m = -1e30f, lsum = 0.f;
    float out[16];
    #pragma unroll
    for (int j = 0; j < 16; ++j) out[j] = 0.f;

    const int maxp = qoff + 31;
    for (int kt = 0; kt <= maxp; kt += 32) {
        const int sr = tid >> 3;
        const int sc = (tid & 7) * 16;
        if (kt + sr < slen) {
            const float* kr_ = k + (size_t)(soff + kt + sr) * H_ + h * HD_ + sc;
            const float* vr_ = v + (size_t)(soff + kt + sr) * H_ + h * HD_ + sc;
            #pragma unroll
            for (int u = 0; u < 4; ++u) {
                *(float4*)&Ks[sr][sc + u * 4] = *(const float4*)&kr_[u * 4];
                *(float4*)&Vs[sr][sc + u * 4] = *(const float4*)&vr_[u * 4];
            }
        }
        __syncthreads();

        const int kmax = p - kt + 1 < 32 ? p - kt + 1 : 32;  // always >= 1 here
        float sc_r[32];
        #pragma unroll
        for (int kk = 0; kk < 32; ++kk) {
            if (kk < kmax) {
                float d = 0.f;
                #pragma unroll
                for (int u = 0; u < 4; ++u) {
                    float4 k4 = *(const float4*)&Ks[kk][l8 * 16 + u * 4];
                    d += qv[u*4+0]*k4.x + qv[u*4+1]*k4.y + qv[u*4+2]*k4.z + qv[u*4+3]*k4.w;
                }
                d += __shfl_xor(d, 1); d += __shfl_xor(d, 2); d += __shfl_xor(d, 4);
                sc_r[kk] = d * SCALE_;
            } else {
                sc_r[kk] = -1e30f;
            }
        }
        float tm = sc_r[0];
        #pragma unroll
        for (int kk = 1; kk < 32; ++kk) tm = fmaxf(tm, sc_r[kk]);
        const float mn = fmaxf(m, tm);
        const float f  = __expf(m - mn);
        m = mn;
        lsum *= f;
        #pragma unroll
        for (int j = 0; j < 16; ++j) out[j] *= f;
        #pragma unroll
        for (int kk = 0; kk < 32; ++kk) {
            const float w = __expf(sc_r[kk] - mn);   // invalid keys -> 0
            lsum += w;
            #pragma unroll
            for (int u = 0; u < 4; ++u) {
                float4 v4 = *(const float4*)&Vs[kk][l8 * 16 + u * 4];
                out[u*4+0] += w * v4.x;
                out[u*4+1] += w * v4.y;
                out[u*4+2] += w * v4.z;
                out[u*4+3] += w * v4.w;
            }
        }
        __syncthreads();
    }
    const float inv = 1.f / lsum;
    float* ar = attn + (size_t)grow * H_ + h * HD_;
    #pragma unroll
    for (int j = 0; j < 16; ++j) ar[l8 * 16 + j] = out[j] * inv;
}

// ---------------------------------------------------------------- decode attention
__global__ __launch_bounds__(256)
void decode_attn_kernel(const float* __restrict__ qb_, const float* __restrict__ kb_,
                        const float* __restrict__ vb_, const float* __restrict__ kc,
                        const float* __restrict__ vc, const int* __restrict__ kv_lens,
                        const float* __restrict__ cost, const float* __restrict__ sint,
                        float* __restrict__ attn)
{
    const int b = blockIdx.x, h = blockIdx.y;
    const int kvlen = kv_lens[b];
    const int L = kvlen + 1;
    const int tid = threadIdx.x, lane = tid & 63, w = tid >> 6;

    __shared__ float sc_s[LMAX_];
    __shared__ float red[4];
    __shared__ float oacc[HD_];

    const float* qrow = qb_ + (size_t)(DOFF_ + b) * H_ + h * HD_;
    const float q1 = qrow[lane], q2 = qrow[lane + 64];
    const float* kdrow = kb_ + (size_t)(DOFF_ + b) * H_ + h * HD_;

    for (int l = w; l < L; l += 4) {
        const float* src = (l == kvlen) ? kdrow
                                        : kc + (((size_t)b * LMAX_ + l) * NH_ + h) * HD_;
        const float k1 = src[lane], k2 = src[lane + 64];
        const float c = cost[l * 64 + lane], s = sint[l * 64 + lane];
        float d = q1 * (k1 * c - k2 * s) + q2 * (k2 * c + k1 * s);
        #pragma unroll
        for (int off = 1; off < 64; off <<= 1) d += __shfl_xor(d, off);
        if (lane == 0) sc_s[l] = d * SCALE_;
    }
    __syncthreads();

    float mx = -1e30f;
    for (int i = tid; i < L; i += 256) mx = fmaxf(mx, sc_s[i]);
    #pragma unroll
    for (int off = 1; off < 64; off <<= 1) mx = fmaxf(mx, __shfl_xor(mx, off));
    if (lane == 0) red[w] = mx;
    __syncthreads();
    mx = fmaxf(fmaxf(red[0], red[1]), fmaxf(red[2], red[3]));
    __syncthreads();

    float sum = 0.f;
    for (int i = tid; i < L; i += 256) { const float e = __expf(sc_s[i] - mx); sc_s[i] = e; sum += e; }
    #pragma unroll
    for (int off = 1; off < 64; off <<= 1) sum += __shfl_xor(sum, off);
    if (lane == 0) red[w] = sum;
    __syncthreads();
    sum = red[0] + red[1] + red[2] + red[3];
    const float inv = 1.f / sum;

    const int d = tid & 127, team = tid >> 7;
    const float* vdrow = vb_ + (size_t)(DOFF_ + b) * H_ + h * HD_;
    float acc = 0.f;
    for (int l = team; l < L; l += 2) {
        const float* src = (l == kvlen) ? vdrow
                                        : vc + (((size_t)b * LMAX_ + l) * NH_ + h) * HD_;
        acc += sc_s[l] * src[d];
    }
    if (team == 1) oacc[d] = acc;
    __syncthreads();
    if (team == 0) attn[(size_t)(DOFF_ + b) * H_ + h * HD_ + d] = (acc + oacc[d]) * inv;
}

// ---------------------------------------------------------------- host launch
extern "C" void kernel_launch(void* const* d_in, const int* in_sizes, int n_in,
                              void* d_out, int out_size, void* d_ws, size_t ws_size,
                              hipStream_t stream)
{
    const float* hs     = (const float*)d_in[0];
    const float* wq     = (const float*)d_in[1];
    const float* wk     = (const float*)d_in[2];
    const float* wv     = (const float*)d_in[3];
    const float* wo     = (const float*)d_in[4];
    const float* la_q   = (const float*)d_in[5];
    const float* lb_q   = (const float*)d_in[6];
    const float* la_k   = (const float*)d_in[7];
    const float* lb_k   = (const float*)d_in[8];
    const float* la_v   = (const float*)d_in[9];
    const float* lb_v   = (const float*)d_in[10];
    const float* la_o   = (const float*)d_in[11];
    const float* lb_o   = (const float*)d_in[12];
    const float* kcache = (const float*)d_in[13];
    const float* vcache = (const float*)d_in[14];
    const int*   kvlen  = (const int*)d_in[15];
    float* out = (float*)d_out;

    float* qbuf    = (float*)d_ws;
    float* kbuf    = qbuf + (size_t)T_ * H_;
    float* vbuf    = kbuf + (size_t)T_ * H_;
    float* attnbuf = vbuf + (size_t)T_ * H_;
    float* tmpbuf  = attnbuf + (size_t)T_ * H_;
    float* costab  = tmpbuf + (size_t)3 * T_ * RANK_;
    float* sintab  = costab + 1024 * 64;
    __bf16* hsb    = (__bf16*)(sintab + 1024 * 64);       // 2688 x 4096 bf16 (padded rows; reused for attn)
    __bf16* wT     = hsb + (size_t)2688 * H_;             // 3 x 4096 x 4096 bf16 (transposed weights)

    const int MT = (T_ + 127) / 128;  // 21
    const int N8 = T_ * H_ / 8;

    rope_table_kernel<<<dim3(1024), dim3(64), 0, stream>>>(costab, sintab);
    convert_bf16_kernel<<<dim3(2048), dim3(256), 0, stream>>>(hs, hsb, N8);
    transpose_bf16_kernel<<<dim3(128, 128, 3), dim3(256), 0, stream>>>(
        wq, wk, wv, wT, wT + (size_t)H_ * H_, wT + (size_t)2 * H_ * H_);
    gemm_mfma<<<dim3(MT, 32, 3), dim3(256), 0, stream>>>(
        hsb, wT, wT + (size_t)H_ * H_, wT + (size_t)2 * H_ * H_, qbuf, kbuf, vbuf, T_);
    lora_tmp_kernel<<<dim3(T_, 3), dim3(256), 0, stream>>>(hs, la_q, la_k, la_v, tmpbuf);
    lora_add_kernel<<<dim3(T_, 16, 3), dim3(256), 0, stream>>>(tmpbuf, lb_q, lb_k, lb_v, qbuf, kbuf, vbuf);
    rope_apply_kernel<<<dim3(T_, 8), dim3(256), 0, stream>>>(qbuf, kbuf, kvlen, costab, sintab);
    prefill_attn_kernel<<<dim3(80, 32), dim3(256), 0, stream>>>(qbuf, kbuf, vbuf, attnbuf);
    decode_attn_kernel<<<dim3(DEC_, NH_), dim3(256), 0, stream>>>(qbuf, kbuf, vbuf, kcache, vcache,
                                                                  kvlen, costab, sintab, attnbuf);
    convert_bf16_kernel<<<dim3(2048), dim3(256), 0, stream>>>(attnbuf, hsb, N8);
    transpose_bf16_kernel<<<dim3(128, 128, 1), dim3(256), 0, stream>>>(wo, wo, wo, wT, wT, wT);
    gemm_mfma<<<dim3(MT, 32, 1), dim3(256), 0, stream>>>(hsb, wT, wT, wT, out, out, out, T_);
    lora_tmp_kernel<<<dim3(T_, 1), dim3(256), 0, stream>>>(attnbuf, la_o, la_o, la_o, tmpbuf);
    lora_add_kernel<<<dim3(T_, 16, 1), dim3(256), 0, stream>>>(tmpbuf, lb_o, lb_o, lb_o, out, out, out);
}

// Round 3
// 1365.509 us; speedup vs baseline: 2.5651x; 1.7153x over previous
//
#include <hip/hip_runtime.h>
#include <hip/hip_bf16.h>

// LlamaAttentionWithLora on MI355X — round 3.
// Prefill attention moved to MFMA (bf16), fed by bf16 q/k emitted from RoPE and a
// per-head V^T transpose. GEMM unchanged (m97 structure). Attention writes bf16
// directly into the O-GEMM A buffer.

#define H_    4096
#define NH_   32
#define HD_   128
#define T_    2592
#define DOFF_ 2560
#define DEC_  32
#define LMAX_ 512
#define RANK_ 16

__constant__ float SCALE_ = 0.08838834764831845f; // 128^-0.5

typedef __bf16 bf16x8 __attribute__((ext_vector_type(8)));
typedef __bf16 bf16x4 __attribute__((ext_vector_type(4)));
typedef float  f32x4  __attribute__((ext_vector_type(4)));

__device__ __forceinline__ void async_cp16(const __bf16* g, __bf16* l) {
    __builtin_amdgcn_global_load_lds(
        (const __attribute__((address_space(1))) void*)g,
        (__attribute__((address_space(3))) void*)l, 16, 0, 0);
}

// ---------------------------------------------------------------- f32 -> bf16 convert (row-major)
__global__ __launch_bounds__(256)
void convert_bf16_kernel(const float* __restrict__ src, __bf16* __restrict__ dst, int n8)
{
    const int stride = gridDim.x * blockDim.x;
    for (int i = blockIdx.x * blockDim.x + threadIdx.x; i < n8; i += stride) {
        float4 a = ((const float4*)src)[i * 2];
        float4 b = ((const float4*)src)[i * 2 + 1];
        bf16x8 w;
        w[0] = (__bf16)a.x; w[1] = (__bf16)a.y; w[2] = (__bf16)a.z; w[3] = (__bf16)a.w;
        w[4] = (__bf16)b.x; w[5] = (__bf16)b.y; w[6] = (__bf16)b.z; w[7] = (__bf16)b.w;
        ((bf16x8*)dst)[i] = w;
    }
}

// ---------------------------------------------------------------- f32 [K][N] -> bf16 [N][K] transpose
__global__ __launch_bounds__(256)
void transpose_bf16_kernel(const float* __restrict__ W0, const float* __restrict__ W1,
                           const float* __restrict__ W2,
                           __bf16* __restrict__ T0, __bf16* __restrict__ T1, __bf16* __restrict__ T2)
{
    const float* W = (blockIdx.z == 0) ? W0 : (blockIdx.z == 1 ? W1 : W2);
    __bf16* To     = (blockIdx.z == 0) ? T0 : (blockIdx.z == 1 ? T1 : T2);
    __shared__ float s[32][33];
    const int bx = blockIdx.x * 32;
    const int by = blockIdx.y * 32;
    const int r  = threadIdx.x >> 3;
    const int c4 = (threadIdx.x & 7) * 4;
    float4 v = *(const float4*)&W[(size_t)(by + r) * H_ + bx + c4];
    s[r][c4] = v.x; s[r][c4 + 1] = v.y; s[r][c4 + 2] = v.z; s[r][c4 + 3] = v.w;
    __syncthreads();
    bf16x4 o;
    o[0] = (__bf16)s[c4 + 0][r]; o[1] = (__bf16)s[c4 + 1][r];
    o[2] = (__bf16)s[c4 + 2][r]; o[3] = (__bf16)s[c4 + 3][r];
    *(bf16x4*)&To[(size_t)(bx + r) * H_ + by + c4] = o;
}

// ---------------------------------------------------------------- V transpose per head: v[t][h*128+d] -> vT[(h*128+d)*T_ + t]
__global__ __launch_bounds__(256)
void transpose_v_kernel(const float* __restrict__ v, __bf16* __restrict__ vT)
{
    __shared__ float s[64][129];
    const int tb = blockIdx.x;   // token block (64)
    const int h  = blockIdx.y;
    const int tid = threadIdx.x;
    #pragma unroll
    for (int i = 0; i < 8; ++i) {
        const int idx = i * 256 + tid;          // 0..2047
        const int row = idx >> 5;               // 0..63
        const int c4  = (idx & 31) * 4;
        *(float4*)&s[row][c4] = *(const float4*)&v[(size_t)(tb * 64 + row) * H_ + h * HD_ + c4];
    }
    __syncthreads();
    #pragma unroll
    for (int i = 0; i < 4; ++i) {
        const int idx = i * 256 + tid;          // 0..1023
        const int d = idx >> 3;                 // 0..127
        const int c = idx & 7;                  // token chunk of 8
        bf16x8 w;
        #pragma unroll
        for (int j = 0; j < 8; ++j) w[j] = (__bf16)s[c * 8 + j][d];
        *(bf16x8*)&vT[(size_t)(h * HD_ + d) * T_ + tb * 64 + c * 8] = w;
    }
}

// ---------------------------------------------------------------- GEMM C = A @ Bt^T  (m97 structure)
__global__ __launch_bounds__(256)
void gemm_mfma(const __bf16* __restrict__ A,
               const __bf16* __restrict__ Bt0, const __bf16* __restrict__ Bt1,
               const __bf16* __restrict__ Bt2,
               float* __restrict__ C0, float* __restrict__ C1, float* __restrict__ C2, int M)
{
    const __bf16* Bt; float* C;
    if      (blockIdx.z == 0) { Bt = Bt0; C = C0; }
    else if (blockIdx.z == 1) { Bt = Bt1; C = C1; }
    else                      { Bt = Bt2; C = C2; }

    const int bm0 = blockIdx.x * 128;
    const int bn0 = blockIdx.y * 128;

    __shared__ __align__(16) __bf16 As[128 * 32];
    __shared__ __align__(16) __bf16 Bs[128 * 32];

    const int tid = threadIdx.x, lane = tid & 63, wid = tid >> 6;
    const int wm = (wid >> 1) * 64, wn = (wid & 1) * 64;
    const int fr = lane & 15, fq = lane >> 4;

    const int srow = wid * 16 + (lane >> 2);
    const int sk   = (lane & 3) * 8;
    const __bf16* aG = A  + (size_t)(bm0 + srow) * H_ + sk;
    const __bf16* bG = Bt + (size_t)(bn0 + srow) * H_ + sk;
    __bf16* aL = As + wid * 16 * 32;
    __bf16* bL = Bs + wid * 16 * 32;

    f32x4 acc[4][4] = {};

    for (int kt = 0; kt < H_; kt += 32) {
        async_cp16(aG + kt,                 aL);
        async_cp16(aG + kt + (size_t)64*H_, aL + 64 * 32);
        async_cp16(bG + kt,                 bL);
        async_cp16(bG + kt + (size_t)64*H_, bL + 64 * 32);
        __syncthreads();

        bf16x8 af[4], bfr[4];
        #pragma unroll
        for (int i = 0; i < 4; ++i) af[i]  = *(const bf16x8*)&As[(wm + i * 16 + fr) * 32 + fq * 8];
        #pragma unroll
        for (int j = 0; j < 4; ++j) bfr[j] = *(const bf16x8*)&Bs[(wn + j * 16 + fr) * 32 + fq * 8];
        #pragma unroll
        for (int i = 0; i < 4; ++i)
            #pragma unroll
            for (int j = 0; j < 4; ++j)
                acc[i][j] = __builtin_amdgcn_mfma_f32_16x16x32_bf16(af[i], bfr[j], acc[i][j], 0, 0, 0);
        __syncthreads();
    }

    #pragma unroll
    for (int i = 0; i < 4; ++i)
        #pragma unroll
        for (int j = 0; j < 4; ++j)
            #pragma unroll
            for (int r = 0; r < 4; ++r) {
                const int row = bm0 + wm + i * 16 + fq * 4 + r;
                const int col = bn0 + wn + j * 16 + fr;
                if (row < M) C[(size_t)row * H_ + col] = acc[i][j][r];
            }
}

// ---------------------------------------------------------------- LoRA stage 1 (f32 X)
__global__ __launch_bounds__(256)
void lora_tmp_kernel(const float* __restrict__ X,
                     const float* __restrict__ la0, const float* __restrict__ la1,
                     const float* __restrict__ la2, float* __restrict__ tmp)
{
    const int r = blockIdx.x;
    const int z = blockIdx.y;
    const float* la = (z == 0) ? la0 : (z == 1 ? la1 : la2);
    const int si = (r < 648) ? 0 : (r < 1296 ? 1 : (r < 1944 ? 2 : 3));
    const float* wa = la + (size_t)si * H_ * RANK_;
    const int c    = threadIdx.x & 15;
    const int part = threadIdx.x >> 4;
    const float* xr = X + (size_t)r * H_;
    float s = 0.f;
    const int h0 = part * 256;
    for (int h = h0; h < h0 + 256; ++h) s += xr[h] * wa[(size_t)h * RANK_ + c];
    __shared__ float red[16][17];
    red[part][c] = s;
    __syncthreads();
    if (threadIdx.x < 16) {
        float t = 0.f;
        #pragma unroll
        for (int p = 0; p < 16; ++p) t += red[p][threadIdx.x];
        tmp[((size_t)z * T_ + r) * RANK_ + threadIdx.x] = t;
    }
}

// ---------------------------------------------------------------- LoRA stage 1 (bf16 X)
__global__ __launch_bounds__(256)
void lora_tmp_bf16_kernel(const __bf16* __restrict__ X,
                          const float* __restrict__ la, float* __restrict__ tmp)
{
    const int r = blockIdx.x;
    const int si = (r < 648) ? 0 : (r < 1296 ? 1 : (r < 1944 ? 2 : 3));
    const float* wa = la + (size_t)si * H_ * RANK_;
    const int c    = threadIdx.x & 15;
    const int part = threadIdx.x >> 4;
    const __bf16* xr = X + (size_t)r * H_;
    float s = 0.f;
    const int h0 = part * 256;
    for (int h = h0; h < h0 + 256; ++h) s += (float)xr[h] * wa[(size_t)h * RANK_ + c];
    __shared__ float red[16][17];
    red[part][c] = s;
    __syncthreads();
    if (threadIdx.x < 16) {
        float t = 0.f;
        #pragma unroll
        for (int p = 0; p < 16; ++p) t += red[p][threadIdx.x];
        tmp[(size_t)r * RANK_ + threadIdx.x] = t;
    }
}

// ---------------------------------------------------------------- LoRA stage 2: Y += tmp @ wb[seg]
__global__ __launch_bounds__(256)
void lora_add_kernel(const float* __restrict__ tmp,
                     const float* __restrict__ lb0, const float* __restrict__ lb1,
                     const float* __restrict__ lb2,
                     float* __restrict__ Y0, float* __restrict__ Y1, float* __restrict__ Y2)
{
    const int z = blockIdx.z;
    const float* lb = (z == 0) ? lb0 : (z == 1 ? lb1 : lb2);
    float* Y = (z == 0) ? Y0 : (z == 1 ? Y1 : Y2);
    const int r = blockIdx.x;
    const int n = blockIdx.y * 256 + threadIdx.x;
    const int si = (r < 648) ? 0 : (r < 1296 ? 1 : (r < 1944 ? 2 : 3));
    const float* wb = lb + (size_t)si * RANK_ * H_;
    __shared__ float tl[16];
    if (threadIdx.x < 16) tl[threadIdx.x] = tmp[((size_t)z * T_ + r) * RANK_ + threadIdx.x];
    __syncthreads();
    float s = 0.f;
    #pragma unroll
    for (int c = 0; c < 16; ++c) s += tl[c] * wb[(size_t)c * H_ + n];
    Y[(size_t)r * H_ + n] += s;
}

// ---------------------------------------------------------------- RoPE tables (pos 0..1023)
__global__ void rope_table_kernel(float* __restrict__ cost, float* __restrict__ sint)
{
    const int p = blockIdx.x;
    const int i = threadIdx.x;
    const float inv = powf(10000.f, -(float)(2 * i) / (float)HD_);
    const float a = (float)p * inv;
    cost[p * 64 + i] = cosf(a);
    sint[p * 64 + i] = sinf(a);
}

// ---------------------------------------------------------------- RoPE apply (in-place f32 + bf16 emit)
__global__ __launch_bounds__(256)
void rope_apply_kernel(float* __restrict__ q, float* __restrict__ k,
                       const int* __restrict__ kv_lens,
                       const float* __restrict__ cost, const float* __restrict__ sint,
                       __bf16* __restrict__ q16, __bf16* __restrict__ k16)
{
    const int r = blockIdx.x;
    const int idx = blockIdx.y * 256 + threadIdx.x;
    const int h = idx >> 6, i = idx & 63;
    int pos; bool dok;
    if (r < DOFF_) {
        if      (r < 1024) pos = r;
        else if (r < 1536) pos = r - 1024;
        else if (r < 2304) pos = r - 1536;
        else               pos = r - 2304;
        dok = true;
    } else {
        pos = kv_lens[r - DOFF_];
        dok = false;
    }
    const float c = cost[pos * 64 + i];
    const float s = sint[pos * 64 + i];
    const size_t base = (size_t)r * H_ + h * HD_ + i;
    float x1 = q[base], x2 = q[base + 64];
    float y1 = x1 * c - x2 * s, y2 = x2 * c + x1 * s;
    q[base] = y1; q[base + 64] = y2;
    q16[base] = (__bf16)y1; q16[base + 64] = (__bf16)y2;
    x1 = k[base]; x2 = k[base + 64];
    if (dok) {
        y1 = x1 * c - x2 * s; y2 = x2 * c + x1 * s;
        k[base] = y1; k[base + 64] = y2;
        k16[base] = (__bf16)y1; k16[base + 64] = (__bf16)y2;
    } else {
        k16[base] = (__bf16)x1; k16[base + 64] = (__bf16)x2;
    }
}

// ---------------------------------------------------------------- prefill attention (MFMA bf16, flash)
// block = (q-block of 64 rows, head). 4 waves x 16 q-rows. KVBLK=64.
__global__ __launch_bounds__(256)
void prefill_attn_mfma(const __bf16* __restrict__ q16, const __bf16* __restrict__ k16,
                       const __bf16* __restrict__ vT, __bf16* __restrict__ attn16)
{
    const int qb = blockIdx.x;
    int soff, qoff;
    if      (qb < 16) { soff = 0;    qoff = qb * 64; }
    else if (qb < 24) { soff = 1024; qoff = (qb - 16) * 64; }
    else if (qb < 36) { soff = 1536; qoff = (qb - 24) * 64; }
    else              { soff = 2304; qoff = (qb - 36) * 64; }
    const int h = blockIdx.y;

    __shared__ __align__(16) __bf16 Kl[64 * 128];    // [key][k], chunk-swizzled
    __shared__ __align__(16) __bf16 Vl[128 * 64];    // [d][key], chunk-swizzled
    __shared__ __align__(16) __bf16 Pl[4][16 * 64];  // per-wave P, chunk-swizzled

    const int tid = threadIdx.x, lane = tid & 63, wid = tid >> 6;
    const int fr = lane & 15, fq = lane >> 4;

    // Q fragments (A): row = fr, k = ks*32 + fq*8 + j
    const int grow0 = soff + qoff + wid * 16;
    bf16x8 qf[4];
    #pragma unroll
    for (int ks = 0; ks < 4; ++ks)
        qf[ks] = *(const bf16x8*)&q16[(size_t)(grow0 + fr) * H_ + h * HD_ + ks * 32 + fq * 8];

    float m[4], l[4];
    #pragma unroll
    for (int r = 0; r < 4; ++r) { m[r] = -1e30f; l[r] = 0.f; }
    f32x4 o[8] = {};

    const int ntiles = qoff / 64 + 1;
    for (int t = 0; t < ntiles; ++t) {
        const int kt = t * 64;
        // stage K tile: 64 rows x 16 chunks (of 8 bf16); phys chunk = c ^ (row&7)
        #pragma unroll
        for (int i = 0; i < 4; ++i) {
            const int chunk = i * 256 + tid;
            const int row = chunk >> 4, c = chunk & 15;
            async_cp16(k16 + (size_t)(soff + kt + row) * H_ + h * HD_ + ((c ^ (row & 7)) * 8),
                       Kl + (size_t)(i * 256 + wid * 64) * 8);
        }
        // stage V^T tile: 128 rows x 8 chunks; phys chunk = c ^ (row&7)
        #pragma unroll
        for (int i = 0; i < 4; ++i) {
            const int chunk = i * 256 + tid;
            const int row = chunk >> 3, c = chunk & 7;
            async_cp16(vT + (size_t)(h * HD_ + row) * T_ + soff + kt + ((c ^ (row & 7)) * 8),
                       Vl + (size_t)(i * 256 + wid * 64) * 8);
        }
        __syncthreads();

        // QK^T: S[16q][64key], 4 key-frags x 4 k-slices
        f32x4 s[4] = {};
        #pragma unroll
        for (int sub = 0; sub < 4; ++sub)
            #pragma unroll
            for (int ks = 0; ks < 4; ++ks) {
                bf16x8 b = *(const bf16x8*)&Kl[(sub * 16 + fr) * 128 + (((ks * 4 + fq) ^ (fr & 7)) * 8)];
                s[sub] = __builtin_amdgcn_mfma_f32_16x16x32_bf16(qf[ks], b, s[sub], 0, 0, 0);
            }

        // mask + online softmax (C layout: q = fq*4+r, key = sub*16+fr)
        float p[4][4];
        #pragma unroll
        for (int sub = 0; sub < 4; ++sub)
            #pragma unroll
            for (int r = 0; r < 4; ++r) {
                const int qpos = qoff + wid * 16 + fq * 4 + r;
                const int kpos = kt + sub * 16 + fr;
                p[sub][r] = (kpos <= qpos) ? s[sub][r] * SCALE_ : -1e30f;
            }
        float fsc[4];
        #pragma unroll
        for (int r = 0; r < 4; ++r) {
            float tm = fmaxf(fmaxf(p[0][r], p[1][r]), fmaxf(p[2][r], p[3][r]));
            tm = fmaxf(tm, __shfl_xor(tm, 1));
            tm = fmaxf(tm, __shfl_xor(tm, 2));
            tm = fmaxf(tm, __shfl_xor(tm, 4));
            tm = fmaxf(tm, __shfl_xor(tm, 8));
            const float mn = fmaxf(m[r], tm);
            fsc[r] = __expf(m[r] - mn);
            m[r] = mn;
            float ls = 0.f;
            #pragma unroll
            for (int sub = 0; sub < 4; ++sub) {
                p[sub][r] = __expf(p[sub][r] - mn);
                ls += p[sub][r];
            }
            l[r] = l[r] * fsc[r] + ls;
        }
        #pragma unroll
        for (int c = 0; c < 8; ++c)
            #pragma unroll
            for (int r = 0; r < 4; ++r) o[c][r] *= fsc[r];

        // write P to per-wave LDS (swizzled), reread as A-fragments
        #pragma unroll
        for (int sub = 0; sub < 4; ++sub)
            #pragma unroll
            for (int r = 0; r < 4; ++r) {
                const int qr = fq * 4 + r;
                Pl[wid][qr * 64 + ((sub * 16 + fr) ^ ((qr & 7) << 3))] = (__bf16)p[sub][r];
            }
        bf16x8 pa[2];
        #pragma unroll
        for (int a = 0; a < 2; ++a)
            pa[a] = *(const bf16x8*)&Pl[wid][fr * 64 + (((a * 4 + fq) ^ (fr & 7)) * 8)];

        // PV: O[16q][128d] += P @ V
        #pragma unroll
        for (int a = 0; a < 2; ++a)
            #pragma unroll
            for (int c = 0; c < 8; ++c) {
                bf16x8 bv = *(const bf16x8*)&Vl[(c * 16 + fr) * 64 + (((a * 4 + fq) ^ (fr & 7)) * 8)];
                o[c] = __builtin_amdgcn_mfma_f32_16x16x32_bf16(pa[a], bv, o[c], 0, 0, 0);
            }
        __syncthreads();
    }

    // reduce l across the 16 key-lanes, normalize, store bf16
    float inv[4];
    #pragma unroll
    for (int r = 0; r < 4; ++r) {
        float ls = l[r];
        ls += __shfl_xor(ls, 1); ls += __shfl_xor(ls, 2);
        ls += __shfl_xor(ls, 4); ls += __shfl_xor(ls, 8);
        inv[r] = 1.f / ls;
    }
    #pragma unroll
    for (int c = 0; c < 8; ++c)
        #pragma unroll
        for (int r = 0; r < 4; ++r)
            attn16[(size_t)(grow0 + fq * 4 + r) * H_ + h * HD_ + c * 16 + fr] = (__bf16)(o[c][r] * inv[r]);
}

// ---------------------------------------------------------------- decode attention (f32, bf16 out)
__global__ __launch_bounds__(256)
void decode_attn_kernel(const float* __restrict__ qb_, const float* __restrict__ kb_,
                        const float* __restrict__ vb_, const float* __restrict__ kc,
                        const float* __restrict__ vc, const int* __restrict__ kv_lens,
                        const float* __restrict__ cost, const float* __restrict__ sint,
                        __bf16* __restrict__ attn16)
{
    const int b = blockIdx.x, h = blockIdx.y;
    const int kvlen = kv_lens[b];
    const int L = kvlen + 1;
    const int tid = threadIdx.x, lane = tid & 63, w = tid >> 6;

    __shared__ float sc_s[LMAX_];
    __shared__ float red[4];
    __shared__ float oacc[HD_];

    const float* qrow = qb_ + (size_t)(DOFF_ + b) * H_ + h * HD_;
    const float q1 = qrow[lane], q2 = qrow[lane + 64];
    const float* kdrow = kb_ + (size_t)(DOFF_ + b) * H_ + h * HD_;

    for (int l = w; l < L; l += 4) {
        const float* src = (l == kvlen) ? kdrow
                                        : kc + (((size_t)b * LMAX_ + l) * NH_ + h) * HD_;
        const float k1 = src[lane], k2 = src[lane + 64];
        const float c = cost[l * 64 + lane], s = sint[l * 64 + lane];
        float d = q1 * (k1 * c - k2 * s) + q2 * (k2 * c + k1 * s);
        #pragma unroll
        for (int off = 1; off < 64; off <<= 1) d += __shfl_xor(d, off);
        if (lane == 0) sc_s[l] = d * SCALE_;
    }
    __syncthreads();

    float mx = -1e30f;
    for (int i = tid; i < L; i += 256) mx = fmaxf(mx, sc_s[i]);
    #pragma unroll
    for (int off = 1; off < 64; off <<= 1) mx = fmaxf(mx, __shfl_xor(mx, off));
    if (lane == 0) red[w] = mx;
    __syncthreads();
    mx = fmaxf(fmaxf(red[0], red[1]), fmaxf(red[2], red[3]));
    __syncthreads();

    float sum = 0.f;
    for (int i = tid; i < L; i += 256) { const float e = __expf(sc_s[i] - mx); sc_s[i] = e; sum += e; }
    #pragma unroll
    for (int off = 1; off < 64; off <<= 1) sum += __shfl_xor(sum, off);
    if (lane == 0) red[w] = sum;
    __syncthreads();
    sum = red[0] + red[1] + red[2] + red[3];
    const float inv = 1.f / sum;

    const int d = tid & 127, team = tid >> 7;
    const float* vdrow = vb_ + (size_t)(DOFF_ + b) * H_ + h * HD_;
    float acc = 0.f;
    for (int l = team; l < L; l += 2) {
        const float* src = (l == kvlen) ? vdrow
                                        : vc + (((size_t)b * LMAX_ + l) * NH_ + h) * HD_;
        acc += sc_s[l] * src[d];
    }
    if (team == 1) oacc[d] = acc;
    __syncthreads();
    if (team == 0) attn16[(size_t)(DOFF_ + b) * H_ + h * HD_ + d] = (__bf16)((acc + oacc[d]) * inv);
}

// ---------------------------------------------------------------- host launch
extern "C" void kernel_launch(void* const* d_in, const int* in_sizes, int n_in,
                              void* d_out, int out_size, void* d_ws, size_t ws_size,
                              hipStream_t stream)
{
    const float* hs     = (const float*)d_in[0];
    const float* wq     = (const float*)d_in[1];
    const float* wk     = (const float*)d_in[2];
    const float* wv     = (const float*)d_in[3];
    const float* wo     = (const float*)d_in[4];
    const float* la_q   = (const float*)d_in[5];
    const float* lb_q   = (const float*)d_in[6];
    const float* la_k   = (const float*)d_in[7];
    const float* lb_k   = (const float*)d_in[8];
    const float* la_v   = (const float*)d_in[9];
    const float* lb_v   = (const float*)d_in[10];
    const float* la_o   = (const float*)d_in[11];
    const float* lb_o   = (const float*)d_in[12];
    const float* kcache = (const float*)d_in[13];
    const float* vcache = (const float*)d_in[14];
    const int*   kvlen  = (const int*)d_in[15];
    float* out = (float*)d_out;

    float* qbuf    = (float*)d_ws;
    float* kbuf    = qbuf + (size_t)T_ * H_;
    float* vbuf    = kbuf + (size_t)T_ * H_;
    float* attnf   = vbuf + (size_t)T_ * H_;          // region reused for q16/k16
    float* tmpbuf  = attnf + (size_t)T_ * H_;
    float* costab  = tmpbuf + (size_t)3 * T_ * RANK_;
    float* sintab  = costab + 1024 * 64;
    __bf16* hsb    = (__bf16*)(sintab + 1024 * 64);   // 2688 x 4096: hs bf16, later attn bf16
    __bf16* wT     = hsb + (size_t)2688 * H_;         // 3 x H x H bf16

    __bf16* q16 = (__bf16*)attnf;                     // T_ x H
    __bf16* k16 = q16 + (size_t)T_ * H_;              // T_ x H
    __bf16* vT  = wT + (size_t)H_ * H_;               // reuse wk^T region after QKV GEMM (H x T_)
    __bf16* attn16 = hsb;                             // attention output (bf16), O-GEMM A operand

    const int MT = (T_ + 127) / 128;  // 21
    const int N8 = T_ * H_ / 8;

    rope_table_kernel<<<dim3(1024), dim3(64), 0, stream>>>(costab, sintab);
    convert_bf16_kernel<<<dim3(2048), dim3(256), 0, stream>>>(hs, hsb, N8);
    transpose_bf16_kernel<<<dim3(128, 128, 3), dim3(256), 0, stream>>>(
        wq, wk, wv, wT, wT + (size_t)H_ * H_, wT + (size_t)2 * H_ * H_);
    gemm_mfma<<<dim3(MT, 32, 3), dim3(256), 0, stream>>>(
        hsb, wT, wT + (size_t)H_ * H_, wT + (size_t)2 * H_ * H_, qbuf, kbuf, vbuf, T_);
    lora_tmp_kernel<<<dim3(T_, 3), dim3(256), 0, stream>>>(hs, la_q, la_k, la_v, tmpbuf);
    lora_add_kernel<<<dim3(T_, 16, 3), dim3(256), 0, stream>>>(tmpbuf, lb_q, lb_k, lb_v, qbuf, kbuf, vbuf);
    rope_apply_kernel<<<dim3(T_, 8), dim3(256), 0, stream>>>(qbuf, kbuf, kvlen, costab, sintab, q16, k16);
    transpose_v_kernel<<<dim3(40, 32), dim3(256), 0, stream>>>(vbuf, vT);
    prefill_attn_mfma<<<dim3(40, 32), dim3(256), 0, stream>>>(q16, k16, vT, attn16);
    decode_attn_kernel<<<dim3(DEC_, NH_), dim3(256), 0, stream>>>(qbuf, kbuf, vbuf, kcache, vcache,
                                                                  kvlen, costab, sintab, attn16);
    transpose_bf16_kernel<<<dim3(128, 128, 1), dim3(256), 0, stream>>>(wo, wo, wo, wT, wT, wT);
    gemm_mfma<<<dim3(MT, 32, 1), dim3(256), 0, stream>>>(attn16, wT, wT, wT, out, out, out, T_);
    lora_tmp_bf16_kernel<<<dim3(T_), dim3(256), 0, stream>>>(attn16, la_o, tmpbuf);
    lora_add_kernel<<<dim3(T_, 16, 1), dim3(256), 0, stream>>>(tmpbuf, lb_o, lb_o, lb_o, out, out, out);
}

// Round 4
// 1180.047 us; speedup vs baseline: 2.9682x; 1.1572x over previous
//
#include <hip/hip_runtime.h>
#include <hip/hip_bf16.h>

// LlamaAttentionWithLora on MI355X — round 4.
// GEMM upgraded to the 256^2 8-phase template (T2 swizzle + T3/T4 counted-vmcnt + T5 setprio).
// Everything else as round 3 (MFMA prefill attention, f32 decode, LoRA side-band).

#define H_    4096
#define NH_   32
#define HD_   128
#define T_    2592
#define DOFF_ 2560
#define DEC_  32
#define LMAX_ 512
#define RANK_ 16
#define MPAD_ 2816   // 11 * 256

__constant__ float SCALE_ = 0.08838834764831845f; // 128^-0.5

typedef __bf16 bf16x8 __attribute__((ext_vector_type(8)));
typedef __bf16 bf16x4 __attribute__((ext_vector_type(4)));
typedef float  f32x4  __attribute__((ext_vector_type(4)));

__device__ __forceinline__ void async_cp16(const __bf16* g, __bf16* l) {
    __builtin_amdgcn_global_load_lds(
        (const __attribute__((address_space(1))) void*)g,
        (__attribute__((address_space(3))) void*)l, 16, 0, 0);
}

// ---------------------------------------------------------------- f32 -> bf16 convert (row-major)
__global__ __launch_bounds__(256)
void convert_bf16_kernel(const float* __restrict__ src, __bf16* __restrict__ dst, int n8)
{
    const int stride = gridDim.x * blockDim.x;
    for (int i = blockIdx.x * blockDim.x + threadIdx.x; i < n8; i += stride) {
        float4 a = ((const float4*)src)[i * 2];
        float4 b = ((const float4*)src)[i * 2 + 1];
        bf16x8 w;
        w[0] = (__bf16)a.x; w[1] = (__bf16)a.y; w[2] = (__bf16)a.z; w[3] = (__bf16)a.w;
        w[4] = (__bf16)b.x; w[5] = (__bf16)b.y; w[6] = (__bf16)b.z; w[7] = (__bf16)b.w;
        ((bf16x8*)dst)[i] = w;
    }
}

// ---------------------------------------------------------------- f32 [K][N] -> bf16 [N][K] transpose
__global__ __launch_bounds__(256)
void transpose_bf16_kernel(const float* __restrict__ W0, const float* __restrict__ W1,
                           const float* __restrict__ W2,
                           __bf16* __restrict__ T0, __bf16* __restrict__ T1, __bf16* __restrict__ T2)
{
    const float* W = (blockIdx.z == 0) ? W0 : (blockIdx.z == 1 ? W1 : W2);
    __bf16* To     = (blockIdx.z == 0) ? T0 : (blockIdx.z == 1 ? T1 : T2);
    __shared__ float s[32][33];
    const int bx = blockIdx.x * 32;
    const int by = blockIdx.y * 32;
    const int r  = threadIdx.x >> 3;
    const int c4 = (threadIdx.x & 7) * 4;
    float4 v = *(const float4*)&W[(size_t)(by + r) * H_ + bx + c4];
    s[r][c4] = v.x; s[r][c4 + 1] = v.y; s[r][c4 + 2] = v.z; s[r][c4 + 3] = v.w;
    __syncthreads();
    bf16x4 o;
    o[0] = (__bf16)s[c4 + 0][r]; o[1] = (__bf16)s[c4 + 1][r];
    o[2] = (__bf16)s[c4 + 2][r]; o[3] = (__bf16)s[c4 + 3][r];
    *(bf16x4*)&To[(size_t)(bx + r) * H_ + by + c4] = o;
}

// ---------------------------------------------------------------- V transpose per head
__global__ __launch_bounds__(256)
void transpose_v_kernel(const float* __restrict__ v, __bf16* __restrict__ vT)
{
    __shared__ float s[64][129];
    const int tb = blockIdx.x;
    const int h  = blockIdx.y;
    const int tid = threadIdx.x;
    #pragma unroll
    for (int i = 0; i < 8; ++i) {
        const int idx = i * 256 + tid;
        const int row = idx >> 5;
        const int c4  = (idx & 31) * 4;
        *(float4*)&s[row][c4] = *(const float4*)&v[(size_t)(tb * 64 + row) * H_ + h * HD_ + c4];
    }
    __syncthreads();
    #pragma unroll
    for (int i = 0; i < 4; ++i) {
        const int idx = i * 256 + tid;
        const int d = idx >> 3;
        const int c = idx & 7;
        bf16x8 w;
        #pragma unroll
        for (int j = 0; j < 8; ++j) w[j] = (__bf16)s[c * 8 + j][d];
        *(bf16x8*)&vT[(size_t)(h * HD_ + d) * T_ + tb * 64 + c * 8] = w;
    }
}

// ---------------------------------------------------------------- GEMM 256x256, BK=64, 8-phase
// C = A @ Bt^T. A: MPAD_ x 4096 bf16 rm. Bt: 4096 x 4096 bf16 [n][k]. C: f32 M x 4096.
__global__ __launch_bounds__(512, 2)
void gemm_mfma8(const __bf16* __restrict__ A,
                const __bf16* __restrict__ Bt0, const __bf16* __restrict__ Bt1,
                const __bf16* __restrict__ Bt2,
                float* __restrict__ C0, float* __restrict__ C1, float* __restrict__ C2, int M)
{
    const __bf16* Bt; float* C;
    if      (blockIdx.z == 0) { Bt = Bt0; C = C0; }
    else if (blockIdx.z == 1) { Bt = Bt1; C = C1; }
    else                      { Bt = Bt2; C = C2; }

    const int bm0 = blockIdx.x * 256;
    const int bn0 = blockIdx.y * 256;

    // [buf][mat(A=0,B=1)][kh][256 rows x 32 k], 16KB regions, chunk-swizzled p = c ^ ((row>>1)&3)
    __shared__ __align__(16) __bf16 lds[2][2][2][256 * 32];

    const int tid = threadIdx.x, lane = tid & 63, wid = tid >> 6;
    const int wr = wid >> 2, wc = wid & 3;
    const int fr = lane & 15, fq = lane >> 4;

    // staging geometry: wave covers linear chunks [wid*128, wid*128+128), 2 instrs x 64 lanes
    const int c0 = wid * 128 + lane;
    const int r0 = c0 >> 2, g0 = ((c0 & 3) ^ ((r0 >> 1) & 3)) * 8;
    const int c1 = c0 + 64;
    const int r1 = c1 >> 2, g1 = ((c1 & 3) ^ ((r1 >> 1) & 3)) * 8;

    const __bf16* Ab = A  + (size_t)bm0 * H_;
    const __bf16* Bb = Bt + (size_t)bn0 * H_;

    auto stage = [&](int buf, int mat, int kh, int kt1) {
        const __bf16* G = mat ? Bb : Ab;
        const int kb = kt1 * 64 + kh * 32;
        __bf16* dst = &lds[buf][mat][kh][wid * 1024];
        async_cp16(G + (size_t)r0 * H_ + kb + g0, dst);
        async_cp16(G + (size_t)r1 * H_ + kb + g1, dst + 512);
    };
    auto rdA = [&](int buf, int kh, int mi) -> bf16x8 {
        const int row = wr * 128 + mi * 16 + fr;
        return *(const bf16x8*)&lds[buf][0][kh][row * 32 + ((fq ^ ((row >> 1) & 3)) << 3)];
    };
    auto rdB = [&](int buf, int kh, int nj) -> bf16x8 {
        const int row = wc * 64 + nj * 16 + fr;
        return *(const bf16x8*)&lds[buf][1][kh][row * 32 + ((fq ^ ((row >> 1) & 3)) << 3)];
    };

    f32x4 acc[8][4] = {};

    // prologue: tile 0, order (A kh0, B kh0, A kh1, B kh1)
    stage(0, 0, 0, 0);
    stage(0, 1, 0, 0);
    stage(0, 0, 1, 0);
    stage(0, 1, 1, 0);
    asm volatile("s_waitcnt vmcnt(4)");
    __builtin_amdgcn_sched_barrier(0);
    __builtin_amdgcn_s_barrier();

    const int NT = H_ / 64;  // 64
    for (int kt = 0; kt < NT; ++kt) {
        const int cur = kt & 1, nb = cur ^ 1;
        const bool pf = (kt + 1 < NT);
        bf16x8 af[8], b0, b1;

        // ---- phase 0: kh0, nj {0,1}
        #pragma unroll
        for (int mi = 0; mi < 8; ++mi) af[mi] = rdA(cur, 0, mi);
        b0 = rdB(cur, 0, 0); b1 = rdB(cur, 0, 1);
        if (pf) stage(nb, 0, 0, kt + 1);
        __builtin_amdgcn_s_barrier();
        asm volatile("s_waitcnt lgkmcnt(0)");
        __builtin_amdgcn_sched_barrier(0);
        __builtin_amdgcn_s_setprio(1);
        #pragma unroll
        for (int mi = 0; mi < 8; ++mi) {
            acc[mi][0] = __builtin_amdgcn_mfma_f32_16x16x32_bf16(af[mi], b0, acc[mi][0], 0, 0, 0);
            acc[mi][1] = __builtin_amdgcn_mfma_f32_16x16x32_bf16(af[mi], b1, acc[mi][1], 0, 0, 0);
        }
        __builtin_amdgcn_s_setprio(0);
        __builtin_amdgcn_s_barrier();

        // ---- phase 1: kh0, nj {2,3}
        b0 = rdB(cur, 0, 2); b1 = rdB(cur, 0, 3);
        if (pf) stage(nb, 1, 0, kt + 1);
        if (pf) asm volatile("s_waitcnt vmcnt(4)");     // cur kh1 (oldest 4) landed
        else    asm volatile("s_waitcnt vmcnt(0)");     // last tile: force-land cur kh1
        __builtin_amdgcn_sched_barrier(0);
        __builtin_amdgcn_s_barrier();
        asm volatile("s_waitcnt lgkmcnt(0)");
        __builtin_amdgcn_sched_barrier(0);
        __builtin_amdgcn_s_setprio(1);
        #pragma unroll
        for (int mi = 0; mi < 8; ++mi) {
            acc[mi][2] = __builtin_amdgcn_mfma_f32_16x16x32_bf16(af[mi], b0, acc[mi][2], 0, 0, 0);
            acc[mi][3] = __builtin_amdgcn_mfma_f32_16x16x32_bf16(af[mi], b1, acc[mi][3], 0, 0, 0);
        }
        __builtin_amdgcn_s_setprio(0);
        __builtin_amdgcn_s_barrier();

        // ---- phase 2: kh1, nj {0,1}
        #pragma unroll
        for (int mi = 0; mi < 8; ++mi) af[mi] = rdA(cur, 1, mi);
        b0 = rdB(cur, 1, 0); b1 = rdB(cur, 1, 1);
        if (pf) stage(nb, 0, 1, kt + 1);
        __builtin_amdgcn_s_barrier();
        asm volatile("s_waitcnt lgkmcnt(0)");
        __builtin_amdgcn_sched_barrier(0);
        __builtin_amdgcn_s_setprio(1);
        #pragma unroll
        for (int mi = 0; mi < 8; ++mi) {
            acc[mi][0] = __builtin_amdgcn_mfma_f32_16x16x32_bf16(af[mi], b0, acc[mi][0], 0, 0, 0);
            acc[mi][1] = __builtin_amdgcn_mfma_f32_16x16x32_bf16(af[mi], b1, acc[mi][1], 0, 0, 0);
        }
        __builtin_amdgcn_s_setprio(0);
        __builtin_amdgcn_s_barrier();

        // ---- phase 3: kh1, nj {2,3}
        b0 = rdB(cur, 1, 2); b1 = rdB(cur, 1, 3);
        if (pf) {
            stage(nb, 1, 1, kt + 1);
            asm volatile("s_waitcnt vmcnt(4)");         // next kh0 (oldest 4) landed
            __builtin_amdgcn_sched_barrier(0);
        }
        __builtin_amdgcn_s_barrier();
        asm volatile("s_waitcnt lgkmcnt(0)");
        __builtin_amdgcn_sched_barrier(0);
        __builtin_amdgcn_s_setprio(1);
        #pragma unroll
        for (int mi = 0; mi < 8; ++mi) {
            acc[mi][2] = __builtin_amdgcn_mfma_f32_16x16x32_bf16(af[mi], b0, acc[mi][2], 0, 0, 0);
            acc[mi][3] = __builtin_amdgcn_mfma_f32_16x16x32_bf16(af[mi], b1, acc[mi][3], 0, 0, 0);
        }
        __builtin_amdgcn_s_setprio(0);
        __builtin_amdgcn_s_barrier();
    }

    // epilogue: C row = fq*4 + r (M), col = fr (N) per fragment
    #pragma unroll
    for (int mi = 0; mi < 8; ++mi)
        #pragma unroll
        for (int nj = 0; nj < 4; ++nj)
            #pragma unroll
            for (int r = 0; r < 4; ++r) {
                const int row = bm0 + wr * 128 + mi * 16 + fq * 4 + r;
                const int col = bn0 + wc * 64 + nj * 16 + fr;
                if (row < M) C[(size_t)row * H_ + col] = acc[mi][nj][r];
            }
}

// ---------------------------------------------------------------- LoRA stage 1 (f32 X)
__global__ __launch_bounds__(256)
void lora_tmp_kernel(const float* __restrict__ X,
                     const float* __restrict__ la0, const float* __restrict__ la1,
                     const float* __restrict__ la2, float* __restrict__ tmp)
{
    const int r = blockIdx.x;
    const int z = blockIdx.y;
    const float* la = (z == 0) ? la0 : (z == 1 ? la1 : la2);
    const int si = (r < 648) ? 0 : (r < 1296 ? 1 : (r < 1944 ? 2 : 3));
    const float* wa = la + (size_t)si * H_ * RANK_;
    const int c    = threadIdx.x & 15;
    const int part = threadIdx.x >> 4;
    const float* xr = X + (size_t)r * H_;
    float s = 0.f;
    const int h0 = part * 256;
    for (int h = h0; h < h0 + 256; ++h) s += xr[h] * wa[(size_t)h * RANK_ + c];
    __shared__ float red[16][17];
    red[part][c] = s;
    __syncthreads();
    if (threadIdx.x < 16) {
        float t = 0.f;
        #pragma unroll
        for (int p = 0; p < 16; ++p) t += red[p][threadIdx.x];
        tmp[((size_t)z * T_ + r) * RANK_ + threadIdx.x] = t;
    }
}

// ---------------------------------------------------------------- LoRA stage 1 (bf16 X)
__global__ __launch_bounds__(256)
void lora_tmp_bf16_kernel(const __bf16* __restrict__ X,
                          const float* __restrict__ la, float* __restrict__ tmp)
{
    const int r = blockIdx.x;
    const int si = (r < 648) ? 0 : (r < 1296 ? 1 : (r < 1944 ? 2 : 3));
    const float* wa = la + (size_t)si * H_ * RANK_;
    const int c    = threadIdx.x & 15;
    const int part = threadIdx.x >> 4;
    const __bf16* xr = X + (size_t)r * H_;
    float s = 0.f;
    const int h0 = part * 256;
    for (int h = h0; h < h0 + 256; ++h) s += (float)xr[h] * wa[(size_t)h * RANK_ + c];
    __shared__ float red[16][17];
    red[part][c] = s;
    __syncthreads();
    if (threadIdx.x < 16) {
        float t = 0.f;
        #pragma unroll
        for (int p = 0; p < 16; ++p) t += red[p][threadIdx.x];
        tmp[(size_t)r * RANK_ + threadIdx.x] = t;
    }
}

// ---------------------------------------------------------------- LoRA stage 2
__global__ __launch_bounds__(256)
void lora_add_kernel(const float* __restrict__ tmp,
                     const float* __restrict__ lb0, const float* __restrict__ lb1,
                     const float* __restrict__ lb2,
                     float* __restrict__ Y0, float* __restrict__ Y1, float* __restrict__ Y2)
{
    const int z = blockIdx.z;
    const float* lb = (z == 0) ? lb0 : (z == 1 ? lb1 : lb2);
    float* Y = (z == 0) ? Y0 : (z == 1 ? Y1 : Y2);
    const int r = blockIdx.x;
    const int n = blockIdx.y * 256 + threadIdx.x;
    const int si = (r < 648) ? 0 : (r < 1296 ? 1 : (r < 1944 ? 2 : 3));
    const float* wb = lb + (size_t)si * RANK_ * H_;
    __shared__ float tl[16];
    if (threadIdx.x < 16) tl[threadIdx.x] = tmp[((size_t)z * T_ + r) * RANK_ + threadIdx.x];
    __syncthreads();
    float s = 0.f;
    #pragma unroll
    for (int c = 0; c < 16; ++c) s += tl[c] * wb[(size_t)c * H_ + n];
    Y[(size_t)r * H_ + n] += s;
}

// ---------------------------------------------------------------- RoPE tables
__global__ void rope_table_kernel(float* __restrict__ cost, float* __restrict__ sint)
{
    const int p = blockIdx.x;
    const int i = threadIdx.x;
    const float inv = powf(10000.f, -(float)(2 * i) / (float)HD_);
    const float a = (float)p * inv;
    cost[p * 64 + i] = cosf(a);
    sint[p * 64 + i] = sinf(a);
}

// ---------------------------------------------------------------- RoPE apply (f32 in-place + bf16 emit)
__global__ __launch_bounds__(256)
void rope_apply_kernel(float* __restrict__ q, float* __restrict__ k,
                       const int* __restrict__ kv_lens,
                       const float* __restrict__ cost, const float* __restrict__ sint,
                       __bf16* __restrict__ q16, __bf16* __restrict__ k16)
{
    const int r = blockIdx.x;
    const int idx = blockIdx.y * 256 + threadIdx.x;
    const int h = idx >> 6, i = idx & 63;
    int pos; bool dok;
    if (r < DOFF_) {
        if      (r < 1024) pos = r;
        else if (r < 1536) pos = r - 1024;
        else if (r < 2304) pos = r - 1536;
        else               pos = r - 2304;
        dok = true;
    } else {
        pos = kv_lens[r - DOFF_];
        dok = false;
    }
    const float c = cost[pos * 64 + i];
    const float s = sint[pos * 64 + i];
    const size_t base = (size_t)r * H_ + h * HD_ + i;
    float x1 = q[base], x2 = q[base + 64];
    float y1 = x1 * c - x2 * s, y2 = x2 * c + x1 * s;
    q[base] = y1; q[base + 64] = y2;
    q16[base] = (__bf16)y1; q16[base + 64] = (__bf16)y2;
    x1 = k[base]; x2 = k[base + 64];
    if (dok) {
        y1 = x1 * c - x2 * s; y2 = x2 * c + x1 * s;
        k[base] = y1; k[base + 64] = y2;
        k16[base] = (__bf16)y1; k16[base + 64] = (__bf16)y2;
    } else {
        k16[base] = (__bf16)x1; k16[base + 64] = (__bf16)x2;
    }
}

// ---------------------------------------------------------------- prefill attention (MFMA bf16, flash)
__global__ __launch_bounds__(256)
void prefill_attn_mfma(const __bf16* __restrict__ q16, const __bf16* __restrict__ k16,
                       const __bf16* __restrict__ vT, __bf16* __restrict__ attn16)
{
    const int qb = blockIdx.x;
    int soff, qoff;
    if      (qb < 16) { soff = 0;    qoff = qb * 64; }
    else if (qb < 24) { soff = 1024; qoff = (qb - 16) * 64; }
    else if (qb < 36) { soff = 1536; qoff = (qb - 24) * 64; }
    else              { soff = 2304; qoff = (qb - 36) * 64; }
    const int h = blockIdx.y;

    __shared__ __align__(16) __bf16 Kl[64 * 128];
    __shared__ __align__(16) __bf16 Vl[128 * 64];
    __shared__ __align__(16) __bf16 Pl[4][16 * 64];

    const int tid = threadIdx.x, lane = tid & 63, wid = tid >> 6;
    const int fr = lane & 15, fq = lane >> 4;

    const int grow0 = soff + qoff + wid * 16;
    bf16x8 qf[4];
    #pragma unroll
    for (int ks = 0; ks < 4; ++ks)
        qf[ks] = *(const bf16x8*)&q16[(size_t)(grow0 + fr) * H_ + h * HD_ + ks * 32 + fq * 8];

    float m[4], l[4];
    #pragma unroll
    for (int r = 0; r < 4; ++r) { m[r] = -1e30f; l[r] = 0.f; }
    f32x4 o[8] = {};

    const int ntiles = qoff / 64 + 1;
    for (int t = 0; t < ntiles; ++t) {
        const int kt = t * 64;
        #pragma unroll
        for (int i = 0; i < 4; ++i) {
            const int chunk = i * 256 + tid;
            const int row = chunk >> 4, c = chunk & 15;
            async_cp16(k16 + (size_t)(soff + kt + row) * H_ + h * HD_ + ((c ^ (row & 7)) * 8),
                       Kl + (size_t)(i * 256 + wid * 64) * 8);
        }
        #pragma unroll
        for (int i = 0; i < 4; ++i) {
            const int chunk = i * 256 + tid;
            const int row = chunk >> 3, c = chunk & 7;
            async_cp16(vT + (size_t)(h * HD_ + row) * T_ + soff + kt + ((c ^ (row & 7)) * 8),
                       Vl + (size_t)(i * 256 + wid * 64) * 8);
        }
        __syncthreads();

        f32x4 s[4] = {};
        #pragma unroll
        for (int sub = 0; sub < 4; ++sub)
            #pragma unroll
            for (int ks = 0; ks < 4; ++ks) {
                bf16x8 b = *(const bf16x8*)&Kl[(sub * 16 + fr) * 128 + (((ks * 4 + fq) ^ (fr & 7)) * 8)];
                s[sub] = __builtin_amdgcn_mfma_f32_16x16x32_bf16(qf[ks], b, s[sub], 0, 0, 0);
            }

        float p[4][4];
        #pragma unroll
        for (int sub = 0; sub < 4; ++sub)
            #pragma unroll
            for (int r = 0; r < 4; ++r) {
                const int qpos = qoff + wid * 16 + fq * 4 + r;
                const int kpos = kt + sub * 16 + fr;
                p[sub][r] = (kpos <= qpos) ? s[sub][r] * SCALE_ : -1e30f;
            }
        float fsc[4];
        #pragma unroll
        for (int r = 0; r < 4; ++r) {
            float tm = fmaxf(fmaxf(p[0][r], p[1][r]), fmaxf(p[2][r], p[3][r]));
            tm = fmaxf(tm, __shfl_xor(tm, 1));
            tm = fmaxf(tm, __shfl_xor(tm, 2));
            tm = fmaxf(tm, __shfl_xor(tm, 4));
            tm = fmaxf(tm, __shfl_xor(tm, 8));
            const float mn = fmaxf(m[r], tm);
            fsc[r] = __expf(m[r] - mn);
            m[r] = mn;
            float ls = 0.f;
            #pragma unroll
            for (int sub = 0; sub < 4; ++sub) {
                p[sub][r] = __expf(p[sub][r] - mn);
                ls += p[sub][r];
            }
            l[r] = l[r] * fsc[r] + ls;
        }
        #pragma unroll
        for (int c = 0; c < 8; ++c)
            #pragma unroll
            for (int r = 0; r < 4; ++r) o[c][r] *= fsc[r];

        #pragma unroll
        for (int sub = 0; sub < 4; ++sub)
            #pragma unroll
            for (int r = 0; r < 4; ++r) {
                const int qr = fq * 4 + r;
                Pl[wid][qr * 64 + ((sub * 16 + fr) ^ ((qr & 7) << 3))] = (__bf16)p[sub][r];
            }
        bf16x8 pa[2];
        #pragma unroll
        for (int a = 0; a < 2; ++a)
            pa[a] = *(const bf16x8*)&Pl[wid][fr * 64 + (((a * 4 + fq) ^ (fr & 7)) * 8)];

        #pragma unroll
        for (int a = 0; a < 2; ++a)
            #pragma unroll
            for (int c = 0; c < 8; ++c) {
                bf16x8 bv = *(const bf16x8*)&Vl[(c * 16 + fr) * 64 + (((a * 4 + fq) ^ (fr & 7)) * 8)];
                o[c] = __builtin_amdgcn_mfma_f32_16x16x32_bf16(pa[a], bv, o[c], 0, 0, 0);
            }
        __syncthreads();
    }

    float inv[4];
    #pragma unroll
    for (int r = 0; r < 4; ++r) {
        float ls = l[r];
        ls += __shfl_xor(ls, 1); ls += __shfl_xor(ls, 2);
        ls += __shfl_xor(ls, 4); ls += __shfl_xor(ls, 8);
        inv[r] = 1.f / ls;
    }
    #pragma unroll
    for (int c = 0; c < 8; ++c)
        #pragma unroll
        for (int r = 0; r < 4; ++r)
            attn16[(size_t)(grow0 + fq * 4 + r) * H_ + h * HD_ + c * 16 + fr] = (__bf16)(o[c][r] * inv[r]);
}

// ---------------------------------------------------------------- decode attention
__global__ __launch_bounds__(256)
void decode_attn_kernel(const float* __restrict__ qb_, const float* __restrict__ kb_,
                        const float* __restrict__ vb_, const float* __restrict__ kc,
                        const float* __restrict__ vc, const int* __restrict__ kv_lens,
                        const float* __restrict__ cost, const float* __restrict__ sint,
                        __bf16* __restrict__ attn16)
{
    const int b = blockIdx.x, h = blockIdx.y;
    const int kvlen = kv_lens[b];
    const int L = kvlen + 1;
    const int tid = threadIdx.x, lane = tid & 63, w = tid >> 6;

    __shared__ float sc_s[LMAX_];
    __shared__ float red[4];
    __shared__ float oacc[HD_];

    const float* qrow = qb_ + (size_t)(DOFF_ + b) * H_ + h * HD_;
    const float q1 = qrow[lane], q2 = qrow[lane + 64];
    const float* kdrow = kb_ + (size_t)(DOFF_ + b) * H_ + h * HD_;

    for (int l = w; l < L; l += 4) {
        const float* src = (l == kvlen) ? kdrow
                                        : kc + (((size_t)b * LMAX_ + l) * NH_ + h) * HD_;
        const float k1 = src[lane], k2 = src[lane + 64];
        const float c = cost[l * 64 + lane], s = sint[l * 64 + lane];
        float d = q1 * (k1 * c - k2 * s) + q2 * (k2 * c + k1 * s);
        #pragma unroll
        for (int off = 1; off < 64; off <<= 1) d += __shfl_xor(d, off);
        if (lane == 0) sc_s[l] = d * SCALE_;
    }
    __syncthreads();

    float mx = -1e30f;
    for (int i = tid; i < L; i += 256) mx = fmaxf(mx, sc_s[i]);
    #pragma unroll
    for (int off = 1; off < 64; off <<= 1) mx = fmaxf(mx, __shfl_xor(mx, off));
    if (lane == 0) red[w] = mx;
    __syncthreads();
    mx = fmaxf(fmaxf(red[0], red[1]), fmaxf(red[2], red[3]));
    __syncthreads();

    float sum = 0.f;
    for (int i = tid; i < L; i += 256) { const float e = __expf(sc_s[i] - mx); sc_s[i] = e; sum += e; }
    #pragma unroll
    for (int off = 1; off < 64; off <<= 1) sum += __shfl_xor(sum, off);
    if (lane == 0) red[w] = sum;
    __syncthreads();
    sum = red[0] + red[1] + red[2] + red[3];
    const float inv = 1.f / sum;

    const int d = tid & 127, team = tid >> 7;
    const float* vdrow = vb_ + (size_t)(DOFF_ + b) * H_ + h * HD_;
    float acc = 0.f;
    for (int l = team; l < L; l += 2) {
        const float* src = (l == kvlen) ? vdrow
                                        : vc + (((size_t)b * LMAX_ + l) * NH_ + h) * HD_;
        acc += sc_s[l] * src[d];
    }
    if (team == 1) oacc[d] = acc;
    __syncthreads();
    if (team == 0) attn16[(size_t)(DOFF_ + b) * H_ + h * HD_ + d] = (__bf16)((acc + oacc[d]) * inv);
}

// ---------------------------------------------------------------- host launch
extern "C" void kernel_launch(void* const* d_in, const int* in_sizes, int n_in,
                              void* d_out, int out_size, void* d_ws, size_t ws_size,
                              hipStream_t stream)
{
    const float* hs     = (const float*)d_in[0];
    const float* wq     = (const float*)d_in[1];
    const float* wk     = (const float*)d_in[2];
    const float* wv     = (const float*)d_in[3];
    const float* wo     = (const float*)d_in[4];
    const float* la_q   = (const float*)d_in[5];
    const float* lb_q   = (const float*)d_in[6];
    const float* la_k   = (const float*)d_in[7];
    const float* lb_k   = (const float*)d_in[8];
    const float* la_v   = (const float*)d_in[9];
    const float* lb_v   = (const float*)d_in[10];
    const float* la_o   = (const float*)d_in[11];
    const float* lb_o   = (const float*)d_in[12];
    const float* kcache = (const float*)d_in[13];
    const float* vcache = (const float*)d_in[14];
    const int*   kvlen  = (const int*)d_in[15];
    float* out = (float*)d_out;

    float* qbuf    = (float*)d_ws;
    float* kbuf    = qbuf + (size_t)T_ * H_;
    float* vbuf    = kbuf + (size_t)T_ * H_;
    float* attnf   = vbuf + (size_t)T_ * H_;
    float* tmpbuf  = attnf + (size_t)T_ * H_;
    float* costab  = tmpbuf + (size_t)3 * T_ * RANK_;
    float* sintab  = costab + 1024 * 64;
    __bf16* hsb    = (__bf16*)(sintab + 1024 * 64);   // MPAD_ x H: hs bf16, later attn bf16
    __bf16* wT     = hsb + (size_t)MPAD_ * H_;        // 3 x H x H bf16

    __bf16* q16 = (__bf16*)attnf;
    __bf16* k16 = q16 + (size_t)T_ * H_;
    __bf16* vT  = wT + (size_t)H_ * H_;               // reuse wk^T region after QKV GEMM
    __bf16* attn16 = hsb;

    const int N8 = T_ * H_ / 8;

    rope_table_kernel<<<dim3(1024), dim3(64), 0, stream>>>(costab, sintab);
    convert_bf16_kernel<<<dim3(2048), dim3(256), 0, stream>>>(hs, hsb, N8);
    transpose_bf16_kernel<<<dim3(128, 128, 3), dim3(256), 0, stream>>>(
        wq, wk, wv, wT, wT + (size_t)H_ * H_, wT + (size_t)2 * H_ * H_);
    gemm_mfma8<<<dim3(MPAD_ / 256, 16, 3), dim3(512), 0, stream>>>(
        hsb, wT, wT + (size_t)H_ * H_, wT + (size_t)2 * H_ * H_, qbuf, kbuf, vbuf, T_);
    lora_tmp_kernel<<<dim3(T_, 3), dim3(256), 0, stream>>>(hs, la_q, la_k, la_v, tmpbuf);
    lora_add_kernel<<<dim3(T_, 16, 3), dim3(256), 0, stream>>>(tmpbuf, lb_q, lb_k, lb_v, qbuf, kbuf, vbuf);
    rope_apply_kernel<<<dim3(T_, 8), dim3(256), 0, stream>>>(qbuf, kbuf, kvlen, costab, sintab, q16, k16);
    transpose_v_kernel<<<dim3(40, 32), dim3(256), 0, stream>>>(vbuf, vT);
    prefill_attn_mfma<<<dim3(40, 32), dim3(256), 0, stream>>>(q16, k16, vT, attn16);
    decode_attn_kernel<<<dim3(DEC_, NH_), dim3(256), 0, stream>>>(qbuf, kbuf, vbuf, kcache, vcache,
                                                                  kvlen, costab, sintab, attn16);
    transpose_bf16_kernel<<<dim3(128, 128, 1), dim3(256), 0, stream>>>(wo, wo, wo, wT, wT, wT);
    gemm_mfma8<<<dim3(MPAD_ / 256, 16, 1), dim3(512), 0, stream>>>(
        attn16, wT, wT, wT, out, out, out, T_);
    lora_tmp_bf16_kernel<<<dim3(T_), dim3(256), 0, stream>>>(attn16, la_o, tmpbuf);
    lora_add_kernel<<<dim3(T_, 16, 1), dim3(256), 0, stream>>>(tmpbuf, lb_o, lb_o, lb_o, out, out, out);
}